// Round 17
// baseline (216.771 us; speedup 1.0000x reference)
//
#include <hip/hip_runtime.h>

// 3-layer GAT (PyG GATConv) on MI355X.
// CSR build via two-level counting sort — NO global atomics:
//   A: per-block LDS histogram over coarse buckets (64 nodes each),
//      layer-1 GEMM rides on even blocks (heterogeneous, LDS union).
//   scan: scan1 (block-local) + scan2 (partials); scan3 is FUSED into the
//      consumers (scatter/bucket_csr add bsums[gid>>10] on read).
//   C: re-read chunk, LDS returning-atomic cursors -> scatter PACKED
//      (src | (dst&63)<<17) 4-byte records into bucket regions.
//   D: one block per bucket: LDS 64-hist + scan -> rowst + esrc.
// Layers: gemm_att (micro-tiled LDS GEMM, bf16 H epilogue) -> gat_aggr
// (fused softmax + gather; lane owns CPL adjacent bf16 columns; F/CPL
// lanes per node). Stash stride padded to 136 floats (≡8 mod 32 banks):
// co-wave groups' stashes start on banks {0,8,16,24} — R16's 1.37M 4-way
// bank conflicts (stride 128 ≡ 0 mod 32 put all 4 groups on bank 0) -> 0.
// Mean stays a separate cheap kernel (R10+R15 lesson).

constexpr int BLOCK = 256;
constexpr int NBLK = 512;    // hist/scatter blocks (chunked edge ownership)
constexpr int BSH = 6;       // 64 nodes per bucket
constexpr int MAXNB = 1600;  // max buckets (n <= 102400)

__device__ __forceinline__ float llrelu(float x) { return x >= 0.f ? x : 0.2f * x; }

__device__ __forceinline__ unsigned short f2bf(float f) {
    unsigned int u = __float_as_uint(f);
    u += 0x7FFFu + ((u >> 16) & 1u);  // round-to-nearest-even
    return (unsigned short)(u >> 16);
}

// ---------- GEMM body (H bf16 + attention dots), LDS provided by caller ----------
template <int FIN, int FOUT, bool RELU_IN>
__device__ __forceinline__ void gemm_att_body(
    const float* __restrict__ X, const float* __restrict__ W,
    const float* __restrict__ asrc, const float* __restrict__ adst,
    unsigned short* __restrict__ H, float* __restrict__ Ssrc,
    float* __restrict__ Sdst, int n, int gblk, float* Xs, float* Ws) {
    constexpr int CG = FOUT / 4;
    constexpr int NG = BLOCK / CG;
    constexpr int TN = NG * 4;
    constexpr int S = FIN + 4;

    int tid = threadIdx.x;
    int n0_blk = gblk * TN;

    for (int t = tid; t < FIN * FOUT / 4; t += BLOCK) {
        float4 v = ((const float4*)W)[t];
        *(float4*)&Ws[t * 4] = v;
    }
    constexpr int RW = FIN / 4;
    for (int t = tid; t < TN * RW; t += BLOCK) {
        int r = t / RW, c = t % RW;
        int gr = n0_blk + r;
        if (gr >= n) gr = n - 1;
        float4 v = ((const float4*)(X + (size_t)gr * FIN))[c];
        if (RELU_IN) {
            v.x = fmaxf(v.x, 0.f); v.y = fmaxf(v.y, 0.f);
            v.z = fmaxf(v.z, 0.f); v.w = fmaxf(v.w, 0.f);
        }
        *(float4*)&Xs[r * S + c * 4] = v;
    }
    __syncthreads();

    int tx = tid % CG, ty = tid / CG;
    int c0 = tx * 4, nloc = ty * 4;

    float acc[4][4];
#pragma unroll
    for (int i = 0; i < 4; ++i)
#pragma unroll
        for (int j = 0; j < 4; ++j) acc[i][j] = 0.f;

#pragma unroll 2
    for (int kc = 0; kc < FIN / 4; ++kc) {
        float4 xv[4], wv[4];
#pragma unroll
        for (int i = 0; i < 4; ++i) xv[i] = *(const float4*)&Xs[(nloc + i) * S + kc * 4];
#pragma unroll
        for (int kk = 0; kk < 4; ++kk) wv[kk] = *(const float4*)&Ws[(kc * 4 + kk) * FOUT + c0];
#pragma unroll
        for (int i = 0; i < 4; ++i) {
            float xi0 = xv[i].x, xi1 = xv[i].y, xi2 = xv[i].z, xi3 = xv[i].w;
            acc[i][0] = fmaf(xi0, wv[0].x, acc[i][0]);
            acc[i][1] = fmaf(xi0, wv[0].y, acc[i][1]);
            acc[i][2] = fmaf(xi0, wv[0].z, acc[i][2]);
            acc[i][3] = fmaf(xi0, wv[0].w, acc[i][3]);
            acc[i][0] = fmaf(xi1, wv[1].x, acc[i][0]);
            acc[i][1] = fmaf(xi1, wv[1].y, acc[i][1]);
            acc[i][2] = fmaf(xi1, wv[1].z, acc[i][2]);
            acc[i][3] = fmaf(xi1, wv[1].w, acc[i][3]);
            acc[i][0] = fmaf(xi2, wv[2].x, acc[i][0]);
            acc[i][1] = fmaf(xi2, wv[2].y, acc[i][1]);
            acc[i][2] = fmaf(xi2, wv[2].z, acc[i][2]);
            acc[i][3] = fmaf(xi2, wv[2].w, acc[i][3]);
            acc[i][0] = fmaf(xi3, wv[3].x, acc[i][0]);
            acc[i][1] = fmaf(xi3, wv[3].y, acc[i][1]);
            acc[i][2] = fmaf(xi3, wv[3].z, acc[i][2]);
            acc[i][3] = fmaf(xi3, wv[3].w, acc[i][3]);
        }
    }

    float4 as4 = *(const float4*)&asrc[c0];
    float4 ad4 = *(const float4*)&adst[c0];

#pragma unroll
    for (int i = 0; i < 4; ++i) {
        int node = n0_blk + nloc + i;
        bool ok = node < n;
        if (ok) {
            ushort4 hb;
            hb.x = f2bf(acc[i][0]); hb.y = f2bf(acc[i][1]);
            hb.z = f2bf(acc[i][2]); hb.w = f2bf(acc[i][3]);
            *(ushort4*)&H[(size_t)node * FOUT + c0] = hb;
        }
        float vs = acc[i][0] * as4.x + acc[i][1] * as4.y + acc[i][2] * as4.z + acc[i][3] * as4.w;
        float vd = acc[i][0] * ad4.x + acc[i][1] * ad4.y + acc[i][2] * ad4.z + acc[i][3] * ad4.w;
#pragma unroll
        for (int off = CG / 2; off > 0; off >>= 1) {
            vs += __shfl_xor(vs, off, CG);
            vd += __shfl_xor(vd, off, CG);
        }
        if (tx == 0 && ok) {
            Ssrc[node] = vs;
            Sdst[node] = vd;
        }
    }
}

template <int FIN, int FOUT, bool RELU_IN>
__global__ void gemm_att_kernel(const float* __restrict__ X, const float* __restrict__ W,
                                const float* __restrict__ asrc, const float* __restrict__ adst,
                                unsigned short* __restrict__ H, float* __restrict__ Ssrc,
                                float* __restrict__ Sdst, int n) {
    constexpr int CG = FOUT / 4;
    constexpr int NG = BLOCK / CG;
    constexpr int TN = NG * 4;
    constexpr int S = FIN + 4;
    __shared__ float Xs[TN * S];
    __shared__ float Ws[FIN * FOUT];
    gemm_att_body<FIN, FOUT, RELU_IN>(X, W, asrc, adst, H, Ssrc, Sdst, n, blockIdx.x, Xs, Ws);
}

// ---------- Phase A: coarse histogram (odd blocks) + layer-1 GEMM (even) ----------
__global__ void hist_gemm1_kernel(const float* __restrict__ X, const float* __restrict__ W,
                                  const float* __restrict__ asrc, const float* __restrict__ adst,
                                  unsigned short* __restrict__ H, float* __restrict__ Ssrc,
                                  float* __restrict__ Sdst, int n, int ngemm,
                                  const int* __restrict__ dst, int E, int chunk, int NB,
                                  int* __restrict__ S, float* __restrict__ facc) {
    // LDS union: gemm<64,64> needs 64*68 + 64*64 = 8448 floats; hist needs 1600 ints.
    __shared__ __align__(16) float lds[8448];
    int bid = blockIdx.x;
    if ((bid & 1) == 0) {
        int gb = bid >> 1;
        if (gb >= ngemm) return;
        gemm_att_body<64, 64, false>(X, W, asrc, adst, H, Ssrc, Sdst, n, gb, lds, lds + 64 * 68);
    } else {
        int k = bid >> 1;
        if (k >= NBLK) return;
        int* hist = (int*)lds;
        for (int i = threadIdx.x; i < NB; i += BLOCK) hist[i] = 0;
        if (k == 0 && threadIdx.x < 32) facc[threadIdx.x] = 0.f;
        __syncthreads();
        int start = k * chunk, end = min(E, start + chunk);
        for (int i = start + threadIdx.x; i < end; i += BLOCK)
            atomicAdd(&hist[dst[i] >> BSH], 1);
        __syncthreads();
        for (int b = threadIdx.x; b < NB; b += BLOCK) S[(size_t)b * NBLK + k] = hist[b];
    }
}

// ---------- 2-pass scan over S[NB*NBLK] (pass 3 fused into consumers) ----------
__global__ void scan1_kernel(int* __restrict__ S, int total, int* __restrict__ bsums) {
    __shared__ int s[1024];
    int tid = threadIdx.x;
    int gid = blockIdx.x * 1024 + tid;
    int v = (gid < total) ? S[gid] : 0;
    s[tid] = v;
    for (int off = 1; off < 1024; off <<= 1) {
        __syncthreads();
        int t = (tid >= off) ? s[tid - off] : 0;
        __syncthreads();
        s[tid] += t;
    }
    __syncthreads();
    if (gid < total) S[gid] = s[tid] - v;  // exclusive within block
    if (tid == 1023) bsums[blockIdx.x] = s[tid];
}

// Single-block tiled scan (handles nb > 1024 via carried offset).
__global__ void scan2_kernel(int* __restrict__ bsums, int nb) {
    __shared__ int s[1024];
    __shared__ int carry_s;
    int tid = threadIdx.x;
    if (tid == 0) carry_s = 0;
    __syncthreads();
    for (int base = 0; base < nb; base += 1024) {
        int i = base + tid;
        int v = (i < nb) ? bsums[i] : 0;
        s[tid] = v;
        for (int off = 1; off < 1024; off <<= 1) {
            __syncthreads();
            int t = (tid >= off) ? s[tid - off] : 0;
            __syncthreads();
            s[tid] += t;
        }
        __syncthreads();
        int c = carry_s;
        if (i < nb) bsums[i] = s[tid] - v + c;  // exclusive + carry
        __syncthreads();
        if (tid == 1023) carry_s = c + s[1023];
        __syncthreads();
    }
}

// ---------- Phase C: scatter packed records into bucket regions ----------
// Record: src | (dst&63)<<17  (requires n <= 131072; here n = 100000).
// Global base = S[cell] + bsums[cell>>10] (scan3 fused).
__global__ void scatter_kernel(const int* __restrict__ src, const int* __restrict__ dst,
                               int E, int chunk, int NB, const int* __restrict__ S,
                               const int* __restrict__ bsums, int* __restrict__ pairs) {
    __shared__ int cursor[MAXNB];
    int k = blockIdx.x;
    for (int b = threadIdx.x; b < NB; b += BLOCK) {
        int cell = b * NBLK + k;
        cursor[b] = S[cell] + bsums[cell >> 10];
    }
    __syncthreads();
    int start = k * chunk, end = min(E, start + chunk);
    for (int i = start + threadIdx.x; i < end; i += BLOCK) {
        int d = dst[i], s = src[i];
        int pos = atomicAdd(&cursor[d >> BSH], 1);  // LDS returning atomic
        pairs[pos] = s | ((d & 63) << 17);
    }
}

// ---------- Phase D: per-bucket CSR (rowst + in-bucket dst-sorted esrc) ----------
__global__ void bucket_csr_kernel(const int* __restrict__ pairs, const int* __restrict__ S,
                                  const int* __restrict__ bsums, int NB, int n, int E,
                                  int* __restrict__ rowst, int* __restrict__ esrc) {
    __shared__ int cnt[64], excl[64];
    int b = blockIdx.x;
    if (b >= NB) return;
    int g0 = b * NBLK;
    int base = S[g0] + bsums[g0 >> 10];
    int end = E;
    if (b + 1 < NB) {
        int g1 = (b + 1) * NBLK;
        end = S[g1] + bsums[g1 >> 10];
    }
    int m = end - base;
    if (threadIdx.x < 64) cnt[threadIdx.x] = 0;
    __syncthreads();
    for (int i = threadIdx.x; i < m; i += BLOCK)
        atomicAdd(&cnt[pairs[base + i] >> 17], 1);
    __syncthreads();
    if (threadIdx.x == 0) {
        int run = 0;
        for (int j = 0; j < 64; ++j) { excl[j] = run; run += cnt[j]; }
    }
    __syncthreads();
    int node0 = b << BSH;
    if (threadIdx.x < 64) {
        int node = node0 + threadIdx.x;
        if (node < n) rowst[node] = base + excl[threadIdx.x];
        cnt[threadIdx.x] = excl[threadIdx.x];  // becomes the running cursor
    }
    if (b == NB - 1 && threadIdx.x == 0) rowst[n] = E;
    __syncthreads();
    for (int i = threadIdx.x; i < m; i += BLOCK) {
        int p = pairs[base + i];
        int pos = atomicAdd(&cnt[p >> 17], 1);  // LDS returning atomic
        esrc[base + pos] = p & 0x1FFFF;
    }
}

// ---------- CPL-column gather machinery (exact bf16 unpack) ----------
template <int CPL> struct GatherT;
template <> struct GatherT<2> { using T = unsigned int; };
template <> struct GatherT<4> { using T = uint2; };

__device__ __forceinline__ void unpack_fma(unsigned int p, float w, float* acc) {
    acc[0] = fmaf(w, __uint_as_float(p << 16), acc[0]);
    acc[1] = fmaf(w, __uint_as_float(p & 0xFFFF0000u), acc[1]);
}
__device__ __forceinline__ void unpack_fma(uint2 p, float w, float* acc) {
    acc[0] = fmaf(w, __uint_as_float(p.x << 16), acc[0]);
    acc[1] = fmaf(w, __uint_as_float(p.x & 0xFFFF0000u), acc[1]);
    acc[2] = fmaf(w, __uint_as_float(p.y << 16), acc[2]);
    acc[3] = fmaf(w, __uint_as_float(p.y & 0xFFFF0000u), acc[3]);
}

template <int NBATCH, typename GT>
__device__ __forceinline__ void gather_fma_b(const GT* __restrict__ Hg,
                                             const float* wldsg, const int* ildsg,
                                             int j0, int lane, float* acc) {
    float wv[NBATCH];
    int ix[NBATCH];
#pragma unroll
    for (int q = 0; q < NBATCH / 4; ++q) {
        float4 w = *(const float4*)&wldsg[j0 + q * 4];
        int4 i4 = *(const int4*)&ildsg[j0 + q * 4];
        wv[q * 4 + 0] = w.x; wv[q * 4 + 1] = w.y; wv[q * 4 + 2] = w.z; wv[q * 4 + 3] = w.w;
        ix[q * 4 + 0] = i4.x; ix[q * 4 + 1] = i4.y; ix[q * 4 + 2] = i4.z; ix[q * 4 + 3] = i4.w;
    }
    GT pv[NBATCH];
#pragma unroll
    for (int u = 0; u < NBATCH; ++u) pv[u] = Hg[(size_t)(unsigned)(ix[u] + lane)];
#pragma unroll
    for (int u = 0; u < NBATCH; ++u) unpack_fma(pv[u], wv[u], acc);
}

// ---------- fused softmax + gather core (CPL columns per lane) ----------
// LPN = F/CPL lanes serve one node; lane owns columns [CPL*lane, CPL*lane+CPL).
template <int F, int K, int CPL>
__device__ __forceinline__ void aggr_node_core(
    const unsigned short* __restrict__ H, const float* __restrict__ Ssrc,
    const float* __restrict__ Sdst, const int* __restrict__ row_start,
    const int* __restrict__ esrc, int node, int lane,
    float* wldsg, int* ildsg, float* accOut) {
    constexpr int LPN = F / CPL;
    constexpr int NS = K * LPN;
    using GT = typename GatherT<CPL>::T;
    const GT* Hg = (const GT*)H;
    int rs = row_start[node];
    int deg = row_start[node + 1] - rs;
    float sdi = Sdst[node];
    float selft = llrelu(Ssrc[node] + sdi);

    float wreg[K];
#pragma unroll
    for (int k = 0; k < K; ++k) {
        wldsg[k * LPN + lane] = 0.f;
        ildsg[k * LPN + lane] = node * LPN;  // own row (safe zero-weight tail)
    }

    float m = selft;
#pragma unroll
    for (int k = 0; k < K; ++k) {
        int j = k * LPN + lane;
        if (j < deg) {
            int s = esrc[rs + j];
            float t = llrelu(Ssrc[s] + sdi);
            ildsg[j] = s * LPN;
            wreg[k] = t;
            m = fmaxf(m, t);
        }
    }
    for (int j = NS + lane; j < deg; j += LPN)  // overflow (deg > NS): rare
        m = fmaxf(m, llrelu(Ssrc[esrc[rs + j]] + sdi));
#pragma unroll
    for (int off = LPN / 2; off > 0; off >>= 1) m = fmaxf(m, __shfl_xor(m, off, LPN));

    float selfw = __expf(selft - m);
    float l = (lane == 0) ? selfw : 0.f;
#pragma unroll
    for (int k = 0; k < K; ++k) {
        int j = k * LPN + lane;
        if (j < deg) {
            float e = __expf(wreg[k] - m);
            wldsg[j] = e;
            l += e;
        }
    }
    for (int j = NS + lane; j < deg; j += LPN)
        l += __expf(llrelu(Ssrc[esrc[rs + j]] + sdi) - m);
#pragma unroll
    for (int off = LPN / 2; off > 0; off >>= 1) l += __shfl_xor(l, off, LPN);
    float winv = 1.f / l;

    float acc[CPL];
#pragma unroll
    for (int c = 0; c < CPL; ++c) acc[c] = 0.f;
    GT pself = Hg[(size_t)node * LPN + lane];
    unpack_fma(pself, selfw, acc);

    // pass 3: full 16-slot batches + 8-slot tail (uniform per group).
    int nbv = deg < NS ? deg : NS;
    int nb16 = nbv & ~15;
    int j0 = 0;
    for (; j0 < nb16; j0 += 16) gather_fma_b<16, GT>(Hg, wldsg, ildsg, j0, lane, acc);
    int rem = nbv - nb16;
    if (rem > 8) gather_fma_b<16, GT>(Hg, wldsg, ildsg, j0, lane, acc);
    else if (rem > 0) gather_fma_b<8, GT>(Hg, wldsg, ildsg, j0, lane, acc);

    for (int j = NS; j < deg; ++j) {  // overflow: recompute w_j (rare)
        int s = esrc[rs + j];
        float wj = __expf(llrelu(Ssrc[s] + sdi) - m);
        GT p = Hg[(size_t)s * LPN + lane];
        unpack_fma(p, wj, acc);
    }
#pragma unroll
    for (int c = 0; c < CPL; ++c) accOut[c] = acc[c] * winv;
}

// Standalone aggregation: LPN=F/CPL lanes per node, CPL floats out per lane.
// Stash stride NSP = NS + 8 floats (≡8 mod 32 banks): co-wave groups start
// on banks {0,8,16,24} -> scalar writes 2-way (free), b128 reads conflict-free.
template <int F, int K, int CPL, bool WITH_BIAS>
__global__ void gat_aggr_kernel(const unsigned short* __restrict__ H,
                                const float* __restrict__ Ssrc, const float* __restrict__ Sdst,
                                const int* __restrict__ rowst, const int* __restrict__ esrc,
                                const float* __restrict__ bias, float* __restrict__ OUT, int n) {
    constexpr int LPN = F / CPL;
    constexpr int GPB = BLOCK / LPN;
    constexpr int NSP = K * LPN + 8;  // padded stride (8 floats = 32 B)
    __shared__ __align__(16) float wlds[GPB][NSP];
    __shared__ __align__(16) int ilds[GPB][NSP];
    int tid = threadIdx.x;
    int grp = tid / LPN, lane = tid % LPN;
    int node = blockIdx.x * GPB + grp;
    if (node >= n) return;
    float acc[CPL];
    aggr_node_core<F, K, CPL>(H, Ssrc, Sdst, rowst, esrc, node, lane,
                              wlds[grp], ilds[grp], acc);
    if (WITH_BIAS) {
#pragma unroll
        for (int c = 0; c < CPL; ++c) acc[c] += bias[CPL * lane + c];
    }
    if constexpr (CPL == 4) {
        float4 v = make_float4(acc[0], acc[1], acc[2], acc[3]);
        *(float4*)&OUT[(size_t)node * F + 4 * lane] = v;
    } else {
        float2 v = make_float2(acc[0], acc[1]);
        *(float2*)&OUT[(size_t)node * F + 2 * lane] = v;
    }
}

// Sum OUT3 over nodes into facc[32].
__global__ void mean_kernel(const float* __restrict__ B, float* __restrict__ facc, int n) {
    __shared__ float s[32];
    int lane = threadIdx.x & 31, row = threadIdx.x >> 5;
    float a = 0.f;
    for (int node = blockIdx.x * 8 + row; node < n; node += gridDim.x * 8)
        a += B[(size_t)node * 32 + lane];
    if (threadIdx.x < 32) s[threadIdx.x] = 0.f;
    __syncthreads();
    atomicAdd(&s[lane], a);
    __syncthreads();
    if (threadIdx.x < 32) atomicAdd(&facc[threadIdx.x], s[threadIdx.x]);
}

__global__ void finalize_kernel(const float* __restrict__ facc, const float* __restrict__ b,
                                const float* __restrict__ tdp, const float* __restrict__ cansup,
                                float* __restrict__ out, int n) {
    int f = threadIdx.x;
    if (f < 32) {
        float td = tdp[0] * cansup[0];
        out[f] = (facc[f] / (float)n + b[f]) * td;
    }
}

extern "C" void kernel_launch(void* const* d_in, const int* in_sizes, int n_in,
                              void* d_out, int out_size, void* d_ws, size_t ws_size,
                              hipStream_t stream) {
    const float* x      = (const float*)d_in[0];
    const int* eidx     = (const int*)d_in[1];
    const float* W1     = (const float*)d_in[2];
    const float* as1    = (const float*)d_in[3];
    const float* ad1    = (const float*)d_in[4];
    const float* b1     = (const float*)d_in[5];
    const float* W2     = (const float*)d_in[6];
    const float* as2    = (const float*)d_in[7];
    const float* ad2    = (const float*)d_in[8];
    const float* b2     = (const float*)d_in[9];
    const float* W3     = (const float*)d_in[10];
    const float* as3    = (const float*)d_in[11];
    const float* ad3    = (const float*)d_in[12];
    const float* b3     = (const float*)d_in[13];
    const float* tdp    = (const float*)d_in[14];
    const float* cansup = (const float*)d_in[15];

    const int n = in_sizes[0] / 64;   // 100000 nodes
    const int E = in_sizes[1] / 2;    // 1600000 edges
    const int* srcp = eidx;
    const int* dstp = eidx + E;

    const int NB = (n + 63) >> BSH;           // 1563 buckets
    const int chunk = (E + NBLK - 1) / NBLK;  // edges per hist/scatter block
    const int total = NB * NBLK;              // scan matrix size

    char* ws = (char*)d_ws;
    size_t off = 0;
    auto alloc = [&](size_t bytes) -> void* {
        void* p = ws + off;
        off += (bytes + 255) & ~(size_t)255;
        return p;
    };
    unsigned short* H1 = (unsigned short*)alloc((size_t)n * 64 * sizeof(unsigned short));
    unsigned short* H2 = (unsigned short*)alloc((size_t)n * 32 * sizeof(unsigned short));
    unsigned short* H3 = (unsigned short*)alloc((size_t)n * 32 * sizeof(unsigned short));
    float* B      = (float*)alloc((size_t)n * 64 * sizeof(float));  // f32 layer output
    float* ssA    = (float*)alloc((size_t)n * sizeof(float));
    float* sdA    = (float*)alloc((size_t)n * sizeof(float));
    float* ssB    = (float*)alloc((size_t)n * sizeof(float));
    float* sdB    = (float*)alloc((size_t)n * sizeof(float));
    float* ssC    = (float*)alloc((size_t)n * sizeof(float));
    float* sdC    = (float*)alloc((size_t)n * sizeof(float));
    int*   S      = (int*)alloc((size_t)total * sizeof(int));
    int*   bsums  = (int*)alloc(1024 * sizeof(int));
    int*   rowst  = (int*)alloc((size_t)(n + 1) * sizeof(int));
    int*   esrc   = (int*)alloc((size_t)E * sizeof(int));
    int*   pairs  = (int*)alloc((size_t)E * sizeof(int));
    float* facc   = (float*)alloc(64 * sizeof(float));

    // ---- CSR build (counting sort, no global atomics) + layer-1 GEMM ----
    const int ngemm1 = (n + 63) / 64;
    const int gmax = (ngemm1 > NBLK) ? ngemm1 : NBLK;
    hist_gemm1_kernel<<<2 * gmax, BLOCK, 0, stream>>>(
        x, W1, as1, ad1, H1, ssA, sdA, n, ngemm1, dstp, E, chunk, NB, S, facc);
    int nb1 = (total + 1023) / 1024;
    scan1_kernel<<<nb1, 1024, 0, stream>>>(S, total, bsums);
    scan2_kernel<<<1, 1024, 0, stream>>>(bsums, nb1);
    scatter_kernel<<<NBLK, BLOCK, 0, stream>>>(srcp, dstp, E, chunk, NB, S, bsums, pairs);
    bucket_csr_kernel<<<NB, BLOCK, 0, stream>>>(pairs, S, bsums, NB, n, E, rowst, esrc);

    // ---- layer 1 aggregation (quad-column: 16 lanes/node, 16 nodes/block) ----
    gat_aggr_kernel<64, 8, 4, true><<<(n + 15) / 16, BLOCK, 0, stream>>>(
        H1, ssA, sdA, rowst, esrc, b1, B, n);

    // ---- layer 2 ----
    gemm_att_kernel<64, 32, true><<<(n + 127) / 128, BLOCK, 0, stream>>>(
        B, W2, as2, ad2, H2, ssB, sdB, n);
    gat_aggr_kernel<32, 8, 2, true><<<(n + 15) / 16, BLOCK, 0, stream>>>(
        H2, ssB, sdB, rowst, esrc, b2, B, n);

    // ---- layer 3 ----
    gemm_att_kernel<32, 32, true><<<(n + 127) / 128, BLOCK, 0, stream>>>(
        B, W3, as3, ad3, H3, ssC, sdC, n);
    gat_aggr_kernel<32, 8, 2, false><<<(n + 15) / 16, BLOCK, 0, stream>>>(
        H3, ssC, sdC, rowst, esrc, nullptr, B, n);
    mean_kernel<<<1024, 256, 0, stream>>>(B, facc, n);
    finalize_kernel<<<1, 64, 0, stream>>>(facc, b3, tdp, cansup, (float*)d_out, n);
}

// Round 18
// 216.206 us; speedup vs baseline: 1.0026x; 1.0026x over previous
//
#include <hip/hip_runtime.h>

// 3-layer GAT (PyG GATConv) on MI355X.
// CSR build via two-level counting sort — NO global atomics:
//   A: per-block LDS histogram over coarse buckets (64 nodes each),
//      layer-1 GEMM rides on even blocks (heterogeneous, LDS union).
//   scan: scan1 (block-local) + scan2 (partials); scan3 is FUSED into the
//      consumers (scatter/bucket_csr add bsums[gid>>10] on read).
//   C: re-read chunk, LDS returning-atomic cursors -> scatter PACKED
//      (src | (dst&63)<<17) 4-byte records into bucket regions.
//   D: one block per bucket: LDS 64-hist + scan -> rowst + esrc.
// Layers: gemm_att (micro-tiled LDS GEMM, bf16 H epilogue) -> gat_aggr
// (fused softmax + gather; lane owns CPL adjacent bf16 columns; F/CPL
// lanes per node). R18: K=4 (NS=64 stash slots vs mean deg 17 — K=8 spent
// ~87% of init writes + 6 predicated pass-1/2 iterations on unused slots)
// and init covers only [deg, R) where R is the exact pass-3 read extent.
// Stash stride ≡8 mod 32 banks (R17). Mean separate (R10+R15 lesson).

constexpr int BLOCK = 256;
constexpr int NBLK = 512;    // hist/scatter blocks (chunked edge ownership)
constexpr int BSH = 6;       // 64 nodes per bucket
constexpr int MAXNB = 1600;  // max buckets (n <= 102400)

__device__ __forceinline__ float llrelu(float x) { return x >= 0.f ? x : 0.2f * x; }

__device__ __forceinline__ unsigned short f2bf(float f) {
    unsigned int u = __float_as_uint(f);
    u += 0x7FFFu + ((u >> 16) & 1u);  // round-to-nearest-even
    return (unsigned short)(u >> 16);
}

// ---------- GEMM body (H bf16 + attention dots), LDS provided by caller ----------
template <int FIN, int FOUT, bool RELU_IN>
__device__ __forceinline__ void gemm_att_body(
    const float* __restrict__ X, const float* __restrict__ W,
    const float* __restrict__ asrc, const float* __restrict__ adst,
    unsigned short* __restrict__ H, float* __restrict__ Ssrc,
    float* __restrict__ Sdst, int n, int gblk, float* Xs, float* Ws) {
    constexpr int CG = FOUT / 4;
    constexpr int NG = BLOCK / CG;
    constexpr int TN = NG * 4;
    constexpr int S = FIN + 4;

    int tid = threadIdx.x;
    int n0_blk = gblk * TN;

    for (int t = tid; t < FIN * FOUT / 4; t += BLOCK) {
        float4 v = ((const float4*)W)[t];
        *(float4*)&Ws[t * 4] = v;
    }
    constexpr int RW = FIN / 4;
    for (int t = tid; t < TN * RW; t += BLOCK) {
        int r = t / RW, c = t % RW;
        int gr = n0_blk + r;
        if (gr >= n) gr = n - 1;
        float4 v = ((const float4*)(X + (size_t)gr * FIN))[c];
        if (RELU_IN) {
            v.x = fmaxf(v.x, 0.f); v.y = fmaxf(v.y, 0.f);
            v.z = fmaxf(v.z, 0.f); v.w = fmaxf(v.w, 0.f);
        }
        *(float4*)&Xs[r * S + c * 4] = v;
    }
    __syncthreads();

    int tx = tid % CG, ty = tid / CG;
    int c0 = tx * 4, nloc = ty * 4;

    float acc[4][4];
#pragma unroll
    for (int i = 0; i < 4; ++i)
#pragma unroll
        for (int j = 0; j < 4; ++j) acc[i][j] = 0.f;

#pragma unroll 2
    for (int kc = 0; kc < FIN / 4; ++kc) {
        float4 xv[4], wv[4];
#pragma unroll
        for (int i = 0; i < 4; ++i) xv[i] = *(const float4*)&Xs[(nloc + i) * S + kc * 4];
#pragma unroll
        for (int kk = 0; kk < 4; ++kk) wv[kk] = *(const float4*)&Ws[(kc * 4 + kk) * FOUT + c0];
#pragma unroll
        for (int i = 0; i < 4; ++i) {
            float xi0 = xv[i].x, xi1 = xv[i].y, xi2 = xv[i].z, xi3 = xv[i].w;
            acc[i][0] = fmaf(xi0, wv[0].x, acc[i][0]);
            acc[i][1] = fmaf(xi0, wv[0].y, acc[i][1]);
            acc[i][2] = fmaf(xi0, wv[0].z, acc[i][2]);
            acc[i][3] = fmaf(xi0, wv[0].w, acc[i][3]);
            acc[i][0] = fmaf(xi1, wv[1].x, acc[i][0]);
            acc[i][1] = fmaf(xi1, wv[1].y, acc[i][1]);
            acc[i][2] = fmaf(xi1, wv[1].z, acc[i][2]);
            acc[i][3] = fmaf(xi1, wv[1].w, acc[i][3]);
            acc[i][0] = fmaf(xi2, wv[2].x, acc[i][0]);
            acc[i][1] = fmaf(xi2, wv[2].y, acc[i][1]);
            acc[i][2] = fmaf(xi2, wv[2].z, acc[i][2]);
            acc[i][3] = fmaf(xi2, wv[2].w, acc[i][3]);
            acc[i][0] = fmaf(xi3, wv[3].x, acc[i][0]);
            acc[i][1] = fmaf(xi3, wv[3].y, acc[i][1]);
            acc[i][2] = fmaf(xi3, wv[3].z, acc[i][2]);
            acc[i][3] = fmaf(xi3, wv[3].w, acc[i][3]);
        }
    }

    float4 as4 = *(const float4*)&asrc[c0];
    float4 ad4 = *(const float4*)&adst[c0];

#pragma unroll
    for (int i = 0; i < 4; ++i) {
        int node = n0_blk + nloc + i;
        bool ok = node < n;
        if (ok) {
            ushort4 hb;
            hb.x = f2bf(acc[i][0]); hb.y = f2bf(acc[i][1]);
            hb.z = f2bf(acc[i][2]); hb.w = f2bf(acc[i][3]);
            *(ushort4*)&H[(size_t)node * FOUT + c0] = hb;
        }
        float vs = acc[i][0] * as4.x + acc[i][1] * as4.y + acc[i][2] * as4.z + acc[i][3] * as4.w;
        float vd = acc[i][0] * ad4.x + acc[i][1] * ad4.y + acc[i][2] * ad4.z + acc[i][3] * ad4.w;
#pragma unroll
        for (int off = CG / 2; off > 0; off >>= 1) {
            vs += __shfl_xor(vs, off, CG);
            vd += __shfl_xor(vd, off, CG);
        }
        if (tx == 0 && ok) {
            Ssrc[node] = vs;
            Sdst[node] = vd;
        }
    }
}

template <int FIN, int FOUT, bool RELU_IN>
__global__ void gemm_att_kernel(const float* __restrict__ X, const float* __restrict__ W,
                                const float* __restrict__ asrc, const float* __restrict__ adst,
                                unsigned short* __restrict__ H, float* __restrict__ Ssrc,
                                float* __restrict__ Sdst, int n) {
    constexpr int CG = FOUT / 4;
    constexpr int NG = BLOCK / CG;
    constexpr int TN = NG * 4;
    constexpr int S = FIN + 4;
    __shared__ float Xs[TN * S];
    __shared__ float Ws[FIN * FOUT];
    gemm_att_body<FIN, FOUT, RELU_IN>(X, W, asrc, adst, H, Ssrc, Sdst, n, blockIdx.x, Xs, Ws);
}

// ---------- Phase A: coarse histogram (odd blocks) + layer-1 GEMM (even) ----------
__global__ void hist_gemm1_kernel(const float* __restrict__ X, const float* __restrict__ W,
                                  const float* __restrict__ asrc, const float* __restrict__ adst,
                                  unsigned short* __restrict__ H, float* __restrict__ Ssrc,
                                  float* __restrict__ Sdst, int n, int ngemm,
                                  const int* __restrict__ dst, int E, int chunk, int NB,
                                  int* __restrict__ S, float* __restrict__ facc) {
    // LDS union: gemm<64,64> needs 64*68 + 64*64 = 8448 floats; hist needs 1600 ints.
    __shared__ __align__(16) float lds[8448];
    int bid = blockIdx.x;
    if ((bid & 1) == 0) {
        int gb = bid >> 1;
        if (gb >= ngemm) return;
        gemm_att_body<64, 64, false>(X, W, asrc, adst, H, Ssrc, Sdst, n, gb, lds, lds + 64 * 68);
    } else {
        int k = bid >> 1;
        if (k >= NBLK) return;
        int* hist = (int*)lds;
        for (int i = threadIdx.x; i < NB; i += BLOCK) hist[i] = 0;
        if (k == 0 && threadIdx.x < 32) facc[threadIdx.x] = 0.f;
        __syncthreads();
        int start = k * chunk, end = min(E, start + chunk);
        for (int i = start + threadIdx.x; i < end; i += BLOCK)
            atomicAdd(&hist[dst[i] >> BSH], 1);
        __syncthreads();
        for (int b = threadIdx.x; b < NB; b += BLOCK) S[(size_t)b * NBLK + k] = hist[b];
    }
}

// ---------- 2-pass scan over S[NB*NBLK] (pass 3 fused into consumers) ----------
__global__ void scan1_kernel(int* __restrict__ S, int total, int* __restrict__ bsums) {
    __shared__ int s[1024];
    int tid = threadIdx.x;
    int gid = blockIdx.x * 1024 + tid;
    int v = (gid < total) ? S[gid] : 0;
    s[tid] = v;
    for (int off = 1; off < 1024; off <<= 1) {
        __syncthreads();
        int t = (tid >= off) ? s[tid - off] : 0;
        __syncthreads();
        s[tid] += t;
    }
    __syncthreads();
    if (gid < total) S[gid] = s[tid] - v;  // exclusive within block
    if (tid == 1023) bsums[blockIdx.x] = s[tid];
}

// Single-block tiled scan (handles nb > 1024 via carried offset).
__global__ void scan2_kernel(int* __restrict__ bsums, int nb) {
    __shared__ int s[1024];
    __shared__ int carry_s;
    int tid = threadIdx.x;
    if (tid == 0) carry_s = 0;
    __syncthreads();
    for (int base = 0; base < nb; base += 1024) {
        int i = base + tid;
        int v = (i < nb) ? bsums[i] : 0;
        s[tid] = v;
        for (int off = 1; off < 1024; off <<= 1) {
            __syncthreads();
            int t = (tid >= off) ? s[tid - off] : 0;
            __syncthreads();
            s[tid] += t;
        }
        __syncthreads();
        int c = carry_s;
        if (i < nb) bsums[i] = s[tid] - v + c;  // exclusive + carry
        __syncthreads();
        if (tid == 1023) carry_s = c + s[1023];
        __syncthreads();
    }
}

// ---------- Phase C: scatter packed records into bucket regions ----------
// Record: src | (dst&63)<<17  (requires n <= 131072; here n = 100000).
// Global base = S[cell] + bsums[cell>>10] (scan3 fused).
__global__ void scatter_kernel(const int* __restrict__ src, const int* __restrict__ dst,
                               int E, int chunk, int NB, const int* __restrict__ S,
                               const int* __restrict__ bsums, int* __restrict__ pairs) {
    __shared__ int cursor[MAXNB];
    int k = blockIdx.x;
    for (int b = threadIdx.x; b < NB; b += BLOCK) {
        int cell = b * NBLK + k;
        cursor[b] = S[cell] + bsums[cell >> 10];
    }
    __syncthreads();
    int start = k * chunk, end = min(E, start + chunk);
    for (int i = start + threadIdx.x; i < end; i += BLOCK) {
        int d = dst[i], s = src[i];
        int pos = atomicAdd(&cursor[d >> BSH], 1);  // LDS returning atomic
        pairs[pos] = s | ((d & 63) << 17);
    }
}

// ---------- Phase D: per-bucket CSR (rowst + in-bucket dst-sorted esrc) ----------
__global__ void bucket_csr_kernel(const int* __restrict__ pairs, const int* __restrict__ S,
                                  const int* __restrict__ bsums, int NB, int n, int E,
                                  int* __restrict__ rowst, int* __restrict__ esrc) {
    __shared__ int cnt[64], excl[64];
    int b = blockIdx.x;
    if (b >= NB) return;
    int g0 = b * NBLK;
    int base = S[g0] + bsums[g0 >> 10];
    int end = E;
    if (b + 1 < NB) {
        int g1 = (b + 1) * NBLK;
        end = S[g1] + bsums[g1 >> 10];
    }
    int m = end - base;
    if (threadIdx.x < 64) cnt[threadIdx.x] = 0;
    __syncthreads();
    for (int i = threadIdx.x; i < m; i += BLOCK)
        atomicAdd(&cnt[pairs[base + i] >> 17], 1);
    __syncthreads();
    if (threadIdx.x == 0) {
        int run = 0;
        for (int j = 0; j < 64; ++j) { excl[j] = run; run += cnt[j]; }
    }
    __syncthreads();
    int node0 = b << BSH;
    if (threadIdx.x < 64) {
        int node = node0 + threadIdx.x;
        if (node < n) rowst[node] = base + excl[threadIdx.x];
        cnt[threadIdx.x] = excl[threadIdx.x];  // becomes the running cursor
    }
    if (b == NB - 1 && threadIdx.x == 0) rowst[n] = E;
    __syncthreads();
    for (int i = threadIdx.x; i < m; i += BLOCK) {
        int p = pairs[base + i];
        int pos = atomicAdd(&cnt[p >> 17], 1);  // LDS returning atomic
        esrc[base + pos] = p & 0x1FFFF;
    }
}

// ---------- CPL-column gather machinery (exact bf16 unpack) ----------
template <int CPL> struct GatherT;
template <> struct GatherT<2> { using T = unsigned int; };
template <> struct GatherT<4> { using T = uint2; };

__device__ __forceinline__ void unpack_fma(unsigned int p, float w, float* acc) {
    acc[0] = fmaf(w, __uint_as_float(p << 16), acc[0]);
    acc[1] = fmaf(w, __uint_as_float(p & 0xFFFF0000u), acc[1]);
}
__device__ __forceinline__ void unpack_fma(uint2 p, float w, float* acc) {
    acc[0] = fmaf(w, __uint_as_float(p.x << 16), acc[0]);
    acc[1] = fmaf(w, __uint_as_float(p.x & 0xFFFF0000u), acc[1]);
    acc[2] = fmaf(w, __uint_as_float(p.y << 16), acc[2]);
    acc[3] = fmaf(w, __uint_as_float(p.y & 0xFFFF0000u), acc[3]);
}

template <int NBATCH, typename GT>
__device__ __forceinline__ void gather_fma_b(const GT* __restrict__ Hg,
                                             const float* wldsg, const int* ildsg,
                                             int j0, int lane, float* acc) {
    float wv[NBATCH];
    int ix[NBATCH];
#pragma unroll
    for (int q = 0; q < NBATCH / 4; ++q) {
        float4 w = *(const float4*)&wldsg[j0 + q * 4];
        int4 i4 = *(const int4*)&ildsg[j0 + q * 4];
        wv[q * 4 + 0] = w.x; wv[q * 4 + 1] = w.y; wv[q * 4 + 2] = w.z; wv[q * 4 + 3] = w.w;
        ix[q * 4 + 0] = i4.x; ix[q * 4 + 1] = i4.y; ix[q * 4 + 2] = i4.z; ix[q * 4 + 3] = i4.w;
    }
    GT pv[NBATCH];
#pragma unroll
    for (int u = 0; u < NBATCH; ++u) pv[u] = Hg[(size_t)(unsigned)(ix[u] + lane)];
#pragma unroll
    for (int u = 0; u < NBATCH; ++u) unpack_fma(pv[u], wv[u], acc);
}

// ---------- fused softmax + gather core (CPL columns per lane) ----------
// LPN = F/CPL lanes serve one node; lane owns columns [CPL*lane, CPL*lane+CPL).
// Init covers only [deg, R) — the exact tail pass-3 reads; slots < deg are
// fully written by pass1 (ilds) / pass2 (wlds).
template <int F, int K, int CPL>
__device__ __forceinline__ void aggr_node_core(
    const unsigned short* __restrict__ H, const float* __restrict__ Ssrc,
    const float* __restrict__ Sdst, const int* __restrict__ row_start,
    const int* __restrict__ esrc, int node, int lane,
    float* wldsg, int* ildsg, float* accOut) {
    constexpr int LPN = F / CPL;
    constexpr int NS = K * LPN;
    using GT = typename GatherT<CPL>::T;
    const GT* Hg = (const GT*)H;
    int rs = row_start[node];
    int deg = row_start[node + 1] - rs;
    float sdi = Sdst[node];
    float selft = llrelu(Ssrc[node] + sdi);

    // pass-3 read extent R (16-batches + one 16/8 tail), then tail init
    int nbv = deg < NS ? deg : NS;
    int nb16 = nbv & ~15;
    int rem = nbv - nb16;
    int R = nb16 + (rem > 8 ? 16 : (rem > 0 ? 8 : 0));
    for (int j = deg + lane; j < R; j += LPN) {
        wldsg[j] = 0.f;
        ildsg[j] = node * LPN;  // own row (safe zero-weight tail)
    }

    float wreg[K];
    float m = selft;
#pragma unroll
    for (int k = 0; k < K; ++k) {
        int j = k * LPN + lane;
        if (j < deg) {
            int s = esrc[rs + j];
            float t = llrelu(Ssrc[s] + sdi);
            ildsg[j] = s * LPN;
            wreg[k] = t;
            m = fmaxf(m, t);
        }
    }
    for (int j = NS + lane; j < deg; j += LPN)  // overflow (deg > NS): rare
        m = fmaxf(m, llrelu(Ssrc[esrc[rs + j]] + sdi));
#pragma unroll
    for (int off = LPN / 2; off > 0; off >>= 1) m = fmaxf(m, __shfl_xor(m, off, LPN));

    float selfw = __expf(selft - m);
    float l = (lane == 0) ? selfw : 0.f;
#pragma unroll
    for (int k = 0; k < K; ++k) {
        int j = k * LPN + lane;
        if (j < deg) {
            float e = __expf(wreg[k] - m);
            wldsg[j] = e;
            l += e;
        }
    }
    for (int j = NS + lane; j < deg; j += LPN)
        l += __expf(llrelu(Ssrc[esrc[rs + j]] + sdi) - m);
#pragma unroll
    for (int off = LPN / 2; off > 0; off >>= 1) l += __shfl_xor(l, off, LPN);
    float winv = 1.f / l;

    float acc[CPL];
#pragma unroll
    for (int c = 0; c < CPL; ++c) acc[c] = 0.f;
    GT pself = Hg[(size_t)node * LPN + lane];
    unpack_fma(pself, selfw, acc);

    // pass 3: full 16-slot batches + 8-slot tail (uniform per group).
    int j0 = 0;
    for (; j0 < nb16; j0 += 16) gather_fma_b<16, GT>(Hg, wldsg, ildsg, j0, lane, acc);
    if (rem > 8) gather_fma_b<16, GT>(Hg, wldsg, ildsg, j0, lane, acc);
    else if (rem > 0) gather_fma_b<8, GT>(Hg, wldsg, ildsg, j0, lane, acc);

    for (int j = NS; j < deg; ++j) {  // overflow: recompute w_j (rare)
        int s = esrc[rs + j];
        float wj = __expf(llrelu(Ssrc[s] + sdi) - m);
        GT p = Hg[(size_t)s * LPN + lane];
        unpack_fma(p, wj, acc);
    }
#pragma unroll
    for (int c = 0; c < CPL; ++c) accOut[c] = acc[c] * winv;
}

// Standalone aggregation: LPN=F/CPL lanes per node, CPL floats out per lane.
// Stash stride NSP = NS + 8 floats (≡8 mod 32 banks): co-wave groups start
// on banks {0,8,16,24}.
template <int F, int K, int CPL, bool WITH_BIAS>
__global__ void gat_aggr_kernel(const unsigned short* __restrict__ H,
                                const float* __restrict__ Ssrc, const float* __restrict__ Sdst,
                                const int* __restrict__ rowst, const int* __restrict__ esrc,
                                const float* __restrict__ bias, float* __restrict__ OUT, int n) {
    constexpr int LPN = F / CPL;
    constexpr int GPB = BLOCK / LPN;
    constexpr int NSP = K * LPN + 8;  // padded stride (8 floats = 32 B)
    __shared__ __align__(16) float wlds[GPB][NSP];
    __shared__ __align__(16) int ilds[GPB][NSP];
    int tid = threadIdx.x;
    int grp = tid / LPN, lane = tid % LPN;
    int node = blockIdx.x * GPB + grp;
    if (node >= n) return;
    float acc[CPL];
    aggr_node_core<F, K, CPL>(H, Ssrc, Sdst, rowst, esrc, node, lane,
                              wlds[grp], ilds[grp], acc);
    if (WITH_BIAS) {
#pragma unroll
        for (int c = 0; c < CPL; ++c) acc[c] += bias[CPL * lane + c];
    }
    if constexpr (CPL == 4) {
        float4 v = make_float4(acc[0], acc[1], acc[2], acc[3]);
        *(float4*)&OUT[(size_t)node * F + 4 * lane] = v;
    } else {
        float2 v = make_float2(acc[0], acc[1]);
        *(float2*)&OUT[(size_t)node * F + 2 * lane] = v;
    }
}

// Sum OUT3 over nodes into facc[32].
__global__ void mean_kernel(const float* __restrict__ B, float* __restrict__ facc, int n) {
    __shared__ float s[32];
    int lane = threadIdx.x & 31, row = threadIdx.x >> 5;
    float a = 0.f;
    for (int node = blockIdx.x * 8 + row; node < n; node += gridDim.x * 8)
        a += B[(size_t)node * 32 + lane];
    if (threadIdx.x < 32) s[threadIdx.x] = 0.f;
    __syncthreads();
    atomicAdd(&s[lane], a);
    __syncthreads();
    if (threadIdx.x < 32) atomicAdd(&facc[threadIdx.x], s[threadIdx.x]);
}

__global__ void finalize_kernel(const float* __restrict__ facc, const float* __restrict__ b,
                                const float* __restrict__ tdp, const float* __restrict__ cansup,
                                float* __restrict__ out, int n) {
    int f = threadIdx.x;
    if (f < 32) {
        float td = tdp[0] * cansup[0];
        out[f] = (facc[f] / (float)n + b[f]) * td;
    }
}

extern "C" void kernel_launch(void* const* d_in, const int* in_sizes, int n_in,
                              void* d_out, int out_size, void* d_ws, size_t ws_size,
                              hipStream_t stream) {
    const float* x      = (const float*)d_in[0];
    const int* eidx     = (const int*)d_in[1];
    const float* W1     = (const float*)d_in[2];
    const float* as1    = (const float*)d_in[3];
    const float* ad1    = (const float*)d_in[4];
    const float* b1     = (const float*)d_in[5];
    const float* W2     = (const float*)d_in[6];
    const float* as2    = (const float*)d_in[7];
    const float* ad2    = (const float*)d_in[8];
    const float* b2     = (const float*)d_in[9];
    const float* W3     = (const float*)d_in[10];
    const float* as3    = (const float*)d_in[11];
    const float* ad3    = (const float*)d_in[12];
    const float* b3     = (const float*)d_in[13];
    const float* tdp    = (const float*)d_in[14];
    const float* cansup = (const float*)d_in[15];

    const int n = in_sizes[0] / 64;   // 100000 nodes
    const int E = in_sizes[1] / 2;    // 1600000 edges
    const int* srcp = eidx;
    const int* dstp = eidx + E;

    const int NB = (n + 63) >> BSH;           // 1563 buckets
    const int chunk = (E + NBLK - 1) / NBLK;  // edges per hist/scatter block
    const int total = NB * NBLK;              // scan matrix size

    char* ws = (char*)d_ws;
    size_t off = 0;
    auto alloc = [&](size_t bytes) -> void* {
        void* p = ws + off;
        off += (bytes + 255) & ~(size_t)255;
        return p;
    };
    unsigned short* H1 = (unsigned short*)alloc((size_t)n * 64 * sizeof(unsigned short));
    unsigned short* H2 = (unsigned short*)alloc((size_t)n * 32 * sizeof(unsigned short));
    unsigned short* H3 = (unsigned short*)alloc((size_t)n * 32 * sizeof(unsigned short));
    float* B      = (float*)alloc((size_t)n * 64 * sizeof(float));  // f32 layer output
    float* ssA    = (float*)alloc((size_t)n * sizeof(float));
    float* sdA    = (float*)alloc((size_t)n * sizeof(float));
    float* ssB    = (float*)alloc((size_t)n * sizeof(float));
    float* sdB    = (float*)alloc((size_t)n * sizeof(float));
    float* ssC    = (float*)alloc((size_t)n * sizeof(float));
    float* sdC    = (float*)alloc((size_t)n * sizeof(float));
    int*   S      = (int*)alloc((size_t)total * sizeof(int));
    int*   bsums  = (int*)alloc(1024 * sizeof(int));
    int*   rowst  = (int*)alloc((size_t)(n + 1) * sizeof(int));
    int*   esrc   = (int*)alloc((size_t)E * sizeof(int));
    int*   pairs  = (int*)alloc((size_t)E * sizeof(int));
    float* facc   = (float*)alloc(64 * sizeof(float));

    // ---- CSR build (counting sort, no global atomics) + layer-1 GEMM ----
    const int ngemm1 = (n + 63) / 64;
    const int gmax = (ngemm1 > NBLK) ? ngemm1 : NBLK;
    hist_gemm1_kernel<<<2 * gmax, BLOCK, 0, stream>>>(
        x, W1, as1, ad1, H1, ssA, sdA, n, ngemm1, dstp, E, chunk, NB, S, facc);
    int nb1 = (total + 1023) / 1024;
    scan1_kernel<<<nb1, 1024, 0, stream>>>(S, total, bsums);
    scan2_kernel<<<1, 1024, 0, stream>>>(bsums, nb1);
    scatter_kernel<<<NBLK, BLOCK, 0, stream>>>(srcp, dstp, E, chunk, NB, S, bsums, pairs);
    bucket_csr_kernel<<<NB, BLOCK, 0, stream>>>(pairs, S, bsums, NB, n, E, rowst, esrc);

    // ---- layer 1 aggregation (quad-column: 16 lanes/node, 16 nodes/block) ----
    gat_aggr_kernel<64, 4, 4, true><<<(n + 15) / 16, BLOCK, 0, stream>>>(
        H1, ssA, sdA, rowst, esrc, b1, B, n);

    // ---- layer 2 ----
    gemm_att_kernel<64, 32, true><<<(n + 127) / 128, BLOCK, 0, stream>>>(
        B, W2, as2, ad2, H2, ssB, sdB, n);
    gat_aggr_kernel<32, 4, 2, true><<<(n + 15) / 16, BLOCK, 0, stream>>>(
        H2, ssB, sdB, rowst, esrc, b2, B, n);

    // ---- layer 3 ----
    gemm_att_kernel<32, 32, true><<<(n + 127) / 128, BLOCK, 0, stream>>>(
        B, W3, as3, ad3, H3, ssC, sdC, n);
    gat_aggr_kernel<32, 4, 2, false><<<(n + 15) / 16, BLOCK, 0, stream>>>(
        H3, ssC, sdC, rowst, esrc, nullptr, B, n);
    mean_kernel<<<1024, 256, 0, stream>>>(B, facc, n);
    finalize_kernel<<<1, 64, 0, stream>>>(facc, b3, tdp, cansup, (float*)d_out, n);
}

// Round 19
// 198.553 us; speedup vs baseline: 1.0918x; 1.0889x over previous
//
#include <hip/hip_runtime.h>

// 3-layer GAT (PyG GATConv) on MI355X.
// CSR build via two-level counting sort — NO global atomics (R10).
// Layers: gemm_att (micro-tiled LDS GEMM; epilogue emits H in FP8 e4m3 —
// R19: three null instruction-cut rounds + identical 89MB/45us across
// F=32/F=64 aggrs showed the aggr is random-access HBM-fetch bound;
// fp8 halves bytes AND makes H1/H2/H3 mostly XCD-L2-resident. Attention
// logits stay f32 (computed from exact accs in the gemm), so only the
// message values are quantized) -> gat_aggr (fused softmax + gather;
// lane owns CPL adjacent fp8 columns; F/CPL lanes per node; K=4 stash,
// tail-only init, stride ≡8 mod 32 banks). Mean separate (R10+R15).

constexpr int BLOCK = 256;
constexpr int NBLK = 512;    // hist/scatter blocks (chunked edge ownership)
constexpr int BSH = 6;       // 64 nodes per bucket
constexpr int MAXNB = 1600;  // max buckets (n <= 102400)

__device__ __forceinline__ float llrelu(float x) { return x >= 0.f ? x : 0.2f * x; }

// ---------- GEMM body (H fp8 + attention dots), LDS provided by caller ----------
template <int FIN, int FOUT, bool RELU_IN>
__device__ __forceinline__ void gemm_att_body(
    const float* __restrict__ X, const float* __restrict__ W,
    const float* __restrict__ asrc, const float* __restrict__ adst,
    unsigned char* __restrict__ H, float* __restrict__ Ssrc,
    float* __restrict__ Sdst, int n, int gblk, float* Xs, float* Ws) {
    constexpr int CG = FOUT / 4;
    constexpr int NG = BLOCK / CG;
    constexpr int TN = NG * 4;
    constexpr int S = FIN + 4;

    int tid = threadIdx.x;
    int n0_blk = gblk * TN;

    for (int t = tid; t < FIN * FOUT / 4; t += BLOCK) {
        float4 v = ((const float4*)W)[t];
        *(float4*)&Ws[t * 4] = v;
    }
    constexpr int RW = FIN / 4;
    for (int t = tid; t < TN * RW; t += BLOCK) {
        int r = t / RW, c = t % RW;
        int gr = n0_blk + r;
        if (gr >= n) gr = n - 1;
        float4 v = ((const float4*)(X + (size_t)gr * FIN))[c];
        if (RELU_IN) {
            v.x = fmaxf(v.x, 0.f); v.y = fmaxf(v.y, 0.f);
            v.z = fmaxf(v.z, 0.f); v.w = fmaxf(v.w, 0.f);
        }
        *(float4*)&Xs[r * S + c * 4] = v;
    }
    __syncthreads();

    int tx = tid % CG, ty = tid / CG;
    int c0 = tx * 4, nloc = ty * 4;

    float acc[4][4];
#pragma unroll
    for (int i = 0; i < 4; ++i)
#pragma unroll
        for (int j = 0; j < 4; ++j) acc[i][j] = 0.f;

#pragma unroll 2
    for (int kc = 0; kc < FIN / 4; ++kc) {
        float4 xv[4], wv[4];
#pragma unroll
        for (int i = 0; i < 4; ++i) xv[i] = *(const float4*)&Xs[(nloc + i) * S + kc * 4];
#pragma unroll
        for (int kk = 0; kk < 4; ++kk) wv[kk] = *(const float4*)&Ws[(kc * 4 + kk) * FOUT + c0];
#pragma unroll
        for (int i = 0; i < 4; ++i) {
            float xi0 = xv[i].x, xi1 = xv[i].y, xi2 = xv[i].z, xi3 = xv[i].w;
            acc[i][0] = fmaf(xi0, wv[0].x, acc[i][0]);
            acc[i][1] = fmaf(xi0, wv[0].y, acc[i][1]);
            acc[i][2] = fmaf(xi0, wv[0].z, acc[i][2]);
            acc[i][3] = fmaf(xi0, wv[0].w, acc[i][3]);
            acc[i][0] = fmaf(xi1, wv[1].x, acc[i][0]);
            acc[i][1] = fmaf(xi1, wv[1].y, acc[i][1]);
            acc[i][2] = fmaf(xi1, wv[1].z, acc[i][2]);
            acc[i][3] = fmaf(xi1, wv[1].w, acc[i][3]);
            acc[i][0] = fmaf(xi2, wv[2].x, acc[i][0]);
            acc[i][1] = fmaf(xi2, wv[2].y, acc[i][1]);
            acc[i][2] = fmaf(xi2, wv[2].z, acc[i][2]);
            acc[i][3] = fmaf(xi2, wv[2].w, acc[i][3]);
            acc[i][0] = fmaf(xi3, wv[3].x, acc[i][0]);
            acc[i][1] = fmaf(xi3, wv[3].y, acc[i][1]);
            acc[i][2] = fmaf(xi3, wv[3].z, acc[i][2]);
            acc[i][3] = fmaf(xi3, wv[3].w, acc[i][3]);
        }
    }

    float4 as4 = *(const float4*)&asrc[c0];
    float4 ad4 = *(const float4*)&adst[c0];

#pragma unroll
    for (int i = 0; i < 4; ++i) {
        int node = n0_blk + nloc + i;
        bool ok = node < n;
        if (ok) {
            unsigned int p = 0;
            p = __builtin_amdgcn_cvt_pk_fp8_f32(acc[i][0], acc[i][1], p, false);
            p = __builtin_amdgcn_cvt_pk_fp8_f32(acc[i][2], acc[i][3], p, true);
            *(unsigned int*)&H[(size_t)node * FOUT + c0] = p;
        }
        float vs = acc[i][0] * as4.x + acc[i][1] * as4.y + acc[i][2] * as4.z + acc[i][3] * as4.w;
        float vd = acc[i][0] * ad4.x + acc[i][1] * ad4.y + acc[i][2] * ad4.z + acc[i][3] * ad4.w;
#pragma unroll
        for (int off = CG / 2; off > 0; off >>= 1) {
            vs += __shfl_xor(vs, off, CG);
            vd += __shfl_xor(vd, off, CG);
        }
        if (tx == 0 && ok) {
            Ssrc[node] = vs;
            Sdst[node] = vd;
        }
    }
}

template <int FIN, int FOUT, bool RELU_IN>
__global__ void gemm_att_kernel(const float* __restrict__ X, const float* __restrict__ W,
                                const float* __restrict__ asrc, const float* __restrict__ adst,
                                unsigned char* __restrict__ H, float* __restrict__ Ssrc,
                                float* __restrict__ Sdst, int n) {
    constexpr int CG = FOUT / 4;
    constexpr int NG = BLOCK / CG;
    constexpr int TN = NG * 4;
    constexpr int S = FIN + 4;
    __shared__ float Xs[TN * S];
    __shared__ float Ws[FIN * FOUT];
    gemm_att_body<FIN, FOUT, RELU_IN>(X, W, asrc, adst, H, Ssrc, Sdst, n, blockIdx.x, Xs, Ws);
}

// ---------- Phase A: coarse histogram (odd blocks) + layer-1 GEMM (even) ----------
__global__ void hist_gemm1_kernel(const float* __restrict__ X, const float* __restrict__ W,
                                  const float* __restrict__ asrc, const float* __restrict__ adst,
                                  unsigned char* __restrict__ H, float* __restrict__ Ssrc,
                                  float* __restrict__ Sdst, int n, int ngemm,
                                  const int* __restrict__ dst, int E, int chunk, int NB,
                                  int* __restrict__ S, float* __restrict__ facc) {
    // LDS union: gemm<64,64> needs 64*68 + 64*64 = 8448 floats; hist needs 1600 ints.
    __shared__ __align__(16) float lds[8448];
    int bid = blockIdx.x;
    if ((bid & 1) == 0) {
        int gb = bid >> 1;
        if (gb >= ngemm) return;
        gemm_att_body<64, 64, false>(X, W, asrc, adst, H, Ssrc, Sdst, n, gb, lds, lds + 64 * 68);
    } else {
        int k = bid >> 1;
        if (k >= NBLK) return;
        int* hist = (int*)lds;
        for (int i = threadIdx.x; i < NB; i += BLOCK) hist[i] = 0;
        if (k == 0 && threadIdx.x < 32) facc[threadIdx.x] = 0.f;
        __syncthreads();
        int start = k * chunk, end = min(E, start + chunk);
        for (int i = start + threadIdx.x; i < end; i += BLOCK)
            atomicAdd(&hist[dst[i] >> BSH], 1);
        __syncthreads();
        for (int b = threadIdx.x; b < NB; b += BLOCK) S[(size_t)b * NBLK + k] = hist[b];
    }
}

// ---------- 2-pass scan over S[NB*NBLK] (pass 3 fused into consumers) ----------
__global__ void scan1_kernel(int* __restrict__ S, int total, int* __restrict__ bsums) {
    __shared__ int s[1024];
    int tid = threadIdx.x;
    int gid = blockIdx.x * 1024 + tid;
    int v = (gid < total) ? S[gid] : 0;
    s[tid] = v;
    for (int off = 1; off < 1024; off <<= 1) {
        __syncthreads();
        int t = (tid >= off) ? s[tid - off] : 0;
        __syncthreads();
        s[tid] += t;
    }
    __syncthreads();
    if (gid < total) S[gid] = s[tid] - v;  // exclusive within block
    if (tid == 1023) bsums[blockIdx.x] = s[tid];
}

// Single-block tiled scan (handles nb > 1024 via carried offset).
__global__ void scan2_kernel(int* __restrict__ bsums, int nb) {
    __shared__ int s[1024];
    __shared__ int carry_s;
    int tid = threadIdx.x;
    if (tid == 0) carry_s = 0;
    __syncthreads();
    for (int base = 0; base < nb; base += 1024) {
        int i = base + tid;
        int v = (i < nb) ? bsums[i] : 0;
        s[tid] = v;
        for (int off = 1; off < 1024; off <<= 1) {
            __syncthreads();
            int t = (tid >= off) ? s[tid - off] : 0;
            __syncthreads();
            s[tid] += t;
        }
        __syncthreads();
        int c = carry_s;
        if (i < nb) bsums[i] = s[tid] - v + c;  // exclusive + carry
        __syncthreads();
        if (tid == 1023) carry_s = c + s[1023];
        __syncthreads();
    }
}

// ---------- Phase C: scatter packed records into bucket regions ----------
// Record: src | (dst&63)<<17  (requires n <= 131072; here n = 100000).
// Global base = S[cell] + bsums[cell>>10] (scan3 fused).
__global__ void scatter_kernel(const int* __restrict__ src, const int* __restrict__ dst,
                               int E, int chunk, int NB, const int* __restrict__ S,
                               const int* __restrict__ bsums, int* __restrict__ pairs) {
    __shared__ int cursor[MAXNB];
    int k = blockIdx.x;
    for (int b = threadIdx.x; b < NB; b += BLOCK) {
        int cell = b * NBLK + k;
        cursor[b] = S[cell] + bsums[cell >> 10];
    }
    __syncthreads();
    int start = k * chunk, end = min(E, start + chunk);
    for (int i = start + threadIdx.x; i < end; i += BLOCK) {
        int d = dst[i], s = src[i];
        int pos = atomicAdd(&cursor[d >> BSH], 1);  // LDS returning atomic
        pairs[pos] = s | ((d & 63) << 17);
    }
}

// ---------- Phase D: per-bucket CSR (rowst + in-bucket dst-sorted esrc) ----------
__global__ void bucket_csr_kernel(const int* __restrict__ pairs, const int* __restrict__ S,
                                  const int* __restrict__ bsums, int NB, int n, int E,
                                  int* __restrict__ rowst, int* __restrict__ esrc) {
    __shared__ int cnt[64], excl[64];
    int b = blockIdx.x;
    if (b >= NB) return;
    int g0 = b * NBLK;
    int base = S[g0] + bsums[g0 >> 10];
    int end = E;
    if (b + 1 < NB) {
        int g1 = (b + 1) * NBLK;
        end = S[g1] + bsums[g1 >> 10];
    }
    int m = end - base;
    if (threadIdx.x < 64) cnt[threadIdx.x] = 0;
    __syncthreads();
    for (int i = threadIdx.x; i < m; i += BLOCK)
        atomicAdd(&cnt[pairs[base + i] >> 17], 1);
    __syncthreads();
    if (threadIdx.x == 0) {
        int run = 0;
        for (int j = 0; j < 64; ++j) { excl[j] = run; run += cnt[j]; }
    }
    __syncthreads();
    int node0 = b << BSH;
    if (threadIdx.x < 64) {
        int node = node0 + threadIdx.x;
        if (node < n) rowst[node] = base + excl[threadIdx.x];
        cnt[threadIdx.x] = excl[threadIdx.x];  // becomes the running cursor
    }
    if (b == NB - 1 && threadIdx.x == 0) rowst[n] = E;
    __syncthreads();
    for (int i = threadIdx.x; i < m; i += BLOCK) {
        int p = pairs[base + i];
        int pos = atomicAdd(&cnt[p >> 17], 1);  // LDS returning atomic
        esrc[base + pos] = p & 0x1FFFF;
    }
}

// ---------- CPL-column gather machinery (fp8 e4m3 unpack via HW cvt) ----------
template <int CPL> struct GatherT;
template <> struct GatherT<2> { using T = unsigned short; };  // 2 fp8
template <> struct GatherT<4> { using T = unsigned int; };    // 4 fp8

__device__ __forceinline__ void unpack_fma(unsigned short p, float w, float* acc) {
    unsigned int u = p;
    acc[0] = fmaf(w, __builtin_amdgcn_cvt_f32_fp8(u, 0), acc[0]);
    acc[1] = fmaf(w, __builtin_amdgcn_cvt_f32_fp8(u, 1), acc[1]);
}
__device__ __forceinline__ void unpack_fma(unsigned int p, float w, float* acc) {
    acc[0] = fmaf(w, __builtin_amdgcn_cvt_f32_fp8(p, 0), acc[0]);
    acc[1] = fmaf(w, __builtin_amdgcn_cvt_f32_fp8(p, 1), acc[1]);
    acc[2] = fmaf(w, __builtin_amdgcn_cvt_f32_fp8(p, 2), acc[2]);
    acc[3] = fmaf(w, __builtin_amdgcn_cvt_f32_fp8(p, 3), acc[3]);
}

template <int NBATCH, typename GT>
__device__ __forceinline__ void gather_fma_b(const GT* __restrict__ Hg,
                                             const float* wldsg, const int* ildsg,
                                             int j0, int lane, float* acc) {
    float wv[NBATCH];
    int ix[NBATCH];
#pragma unroll
    for (int q = 0; q < NBATCH / 4; ++q) {
        float4 w = *(const float4*)&wldsg[j0 + q * 4];
        int4 i4 = *(const int4*)&ildsg[j0 + q * 4];
        wv[q * 4 + 0] = w.x; wv[q * 4 + 1] = w.y; wv[q * 4 + 2] = w.z; wv[q * 4 + 3] = w.w;
        ix[q * 4 + 0] = i4.x; ix[q * 4 + 1] = i4.y; ix[q * 4 + 2] = i4.z; ix[q * 4 + 3] = i4.w;
    }
    GT pv[NBATCH];
#pragma unroll
    for (int u = 0; u < NBATCH; ++u) pv[u] = Hg[(size_t)(unsigned)(ix[u] + lane)];
#pragma unroll
    for (int u = 0; u < NBATCH; ++u) unpack_fma(pv[u], wv[u], acc);
}

// ---------- fused softmax + gather core (CPL columns per lane) ----------
// LPN = F/CPL lanes serve one node; lane owns columns [CPL*lane, CPL*lane+CPL).
// Init covers only [deg, R) — the exact tail pass-3 reads.
template <int F, int K, int CPL>
__device__ __forceinline__ void aggr_node_core(
    const unsigned char* __restrict__ H, const float* __restrict__ Ssrc,
    const float* __restrict__ Sdst, const int* __restrict__ row_start,
    const int* __restrict__ esrc, int node, int lane,
    float* wldsg, int* ildsg, float* accOut) {
    constexpr int LPN = F / CPL;
    constexpr int NS = K * LPN;
    using GT = typename GatherT<CPL>::T;
    const GT* Hg = (const GT*)H;
    int rs = row_start[node];
    int deg = row_start[node + 1] - rs;
    float sdi = Sdst[node];
    float selft = llrelu(Ssrc[node] + sdi);

    // pass-3 read extent R (16-batches + one 16/8 tail), then tail init
    int nbv = deg < NS ? deg : NS;
    int nb16 = nbv & ~15;
    int rem = nbv - nb16;
    int R = nb16 + (rem > 8 ? 16 : (rem > 0 ? 8 : 0));
    for (int j = deg + lane; j < R; j += LPN) {
        wldsg[j] = 0.f;
        ildsg[j] = node * LPN;  // own row (safe zero-weight tail)
    }

    float wreg[K];
    float m = selft;
#pragma unroll
    for (int k = 0; k < K; ++k) {
        int j = k * LPN + lane;
        if (j < deg) {
            int s = esrc[rs + j];
            float t = llrelu(Ssrc[s] + sdi);
            ildsg[j] = s * LPN;
            wreg[k] = t;
            m = fmaxf(m, t);
        }
    }
    for (int j = NS + lane; j < deg; j += LPN)  // overflow (deg > NS): rare
        m = fmaxf(m, llrelu(Ssrc[esrc[rs + j]] + sdi));
#pragma unroll
    for (int off = LPN / 2; off > 0; off >>= 1) m = fmaxf(m, __shfl_xor(m, off, LPN));

    float selfw = __expf(selft - m);
    float l = (lane == 0) ? selfw : 0.f;
#pragma unroll
    for (int k = 0; k < K; ++k) {
        int j = k * LPN + lane;
        if (j < deg) {
            float e = __expf(wreg[k] - m);
            wldsg[j] = e;
            l += e;
        }
    }
    for (int j = NS + lane; j < deg; j += LPN)
        l += __expf(llrelu(Ssrc[esrc[rs + j]] + sdi) - m);
#pragma unroll
    for (int off = LPN / 2; off > 0; off >>= 1) l += __shfl_xor(l, off, LPN);
    float winv = 1.f / l;

    float acc[CPL];
#pragma unroll
    for (int c = 0; c < CPL; ++c) acc[c] = 0.f;
    GT pself = Hg[(size_t)node * LPN + lane];
    unpack_fma(pself, selfw, acc);

    // pass 3: full 16-slot batches + 8-slot tail (uniform per group).
    int j0 = 0;
    for (; j0 < nb16; j0 += 16) gather_fma_b<16, GT>(Hg, wldsg, ildsg, j0, lane, acc);
    if (rem > 8) gather_fma_b<16, GT>(Hg, wldsg, ildsg, j0, lane, acc);
    else if (rem > 0) gather_fma_b<8, GT>(Hg, wldsg, ildsg, j0, lane, acc);

    for (int j = NS; j < deg; ++j) {  // overflow: recompute w_j (rare)
        int s = esrc[rs + j];
        float wj = __expf(llrelu(Ssrc[s] + sdi) - m);
        GT p = Hg[(size_t)s * LPN + lane];
        unpack_fma(p, wj, acc);
    }
#pragma unroll
    for (int c = 0; c < CPL; ++c) accOut[c] = acc[c] * winv;
}

// Standalone aggregation: LPN=F/CPL lanes per node, CPL floats out per lane.
// Stash stride NSP = NS + 8 floats (≡8 mod 32 banks).
template <int F, int K, int CPL, bool WITH_BIAS>
__global__ void gat_aggr_kernel(const unsigned char* __restrict__ H,
                                const float* __restrict__ Ssrc, const float* __restrict__ Sdst,
                                const int* __restrict__ rowst, const int* __restrict__ esrc,
                                const float* __restrict__ bias, float* __restrict__ OUT, int n) {
    constexpr int LPN = F / CPL;
    constexpr int GPB = BLOCK / LPN;
    constexpr int NSP = K * LPN + 8;  // padded stride (8 floats = 32 B)
    __shared__ __align__(16) float wlds[GPB][NSP];
    __shared__ __align__(16) int ilds[GPB][NSP];
    int tid = threadIdx.x;
    int grp = tid / LPN, lane = tid % LPN;
    int node = blockIdx.x * GPB + grp;
    if (node >= n) return;
    float acc[CPL];
    aggr_node_core<F, K, CPL>(H, Ssrc, Sdst, rowst, esrc, node, lane,
                              wlds[grp], ilds[grp], acc);
    if (WITH_BIAS) {
#pragma unroll
        for (int c = 0; c < CPL; ++c) acc[c] += bias[CPL * lane + c];
    }
    if constexpr (CPL == 4) {
        float4 v = make_float4(acc[0], acc[1], acc[2], acc[3]);
        *(float4*)&OUT[(size_t)node * F + 4 * lane] = v;
    } else {
        float2 v = make_float2(acc[0], acc[1]);
        *(float2*)&OUT[(size_t)node * F + 2 * lane] = v;
    }
}

// Sum OUT3 over nodes into facc[32].
__global__ void mean_kernel(const float* __restrict__ B, float* __restrict__ facc, int n) {
    __shared__ float s[32];
    int lane = threadIdx.x & 31, row = threadIdx.x >> 5;
    float a = 0.f;
    for (int node = blockIdx.x * 8 + row; node < n; node += gridDim.x * 8)
        a += B[(size_t)node * 32 + lane];
    if (threadIdx.x < 32) s[threadIdx.x] = 0.f;
    __syncthreads();
    atomicAdd(&s[lane], a);
    __syncthreads();
    if (threadIdx.x < 32) atomicAdd(&facc[threadIdx.x], s[threadIdx.x]);
}

__global__ void finalize_kernel(const float* __restrict__ facc, const float* __restrict__ b,
                                const float* __restrict__ tdp, const float* __restrict__ cansup,
                                float* __restrict__ out, int n) {
    int f = threadIdx.x;
    if (f < 32) {
        float td = tdp[0] * cansup[0];
        out[f] = (facc[f] / (float)n + b[f]) * td;
    }
}

extern "C" void kernel_launch(void* const* d_in, const int* in_sizes, int n_in,
                              void* d_out, int out_size, void* d_ws, size_t ws_size,
                              hipStream_t stream) {
    const float* x      = (const float*)d_in[0];
    const int* eidx     = (const int*)d_in[1];
    const float* W1     = (const float*)d_in[2];
    const float* as1    = (const float*)d_in[3];
    const float* ad1    = (const float*)d_in[4];
    const float* b1     = (const float*)d_in[5];
    const float* W2     = (const float*)d_in[6];
    const float* as2    = (const float*)d_in[7];
    const float* ad2    = (const float*)d_in[8];
    const float* b2     = (const float*)d_in[9];
    const float* W3     = (const float*)d_in[10];
    const float* as3    = (const float*)d_in[11];
    const float* ad3    = (const float*)d_in[12];
    const float* b3     = (const float*)d_in[13];
    const float* tdp    = (const float*)d_in[14];
    const float* cansup = (const float*)d_in[15];

    const int n = in_sizes[0] / 64;   // 100000 nodes
    const int E = in_sizes[1] / 2;    // 1600000 edges
    const int* srcp = eidx;
    const int* dstp = eidx + E;

    const int NB = (n + 63) >> BSH;           // 1563 buckets
    const int chunk = (E + NBLK - 1) / NBLK;  // edges per hist/scatter block
    const int total = NB * NBLK;              // scan matrix size

    char* ws = (char*)d_ws;
    size_t off = 0;
    auto alloc = [&](size_t bytes) -> void* {
        void* p = ws + off;
        off += (bytes + 255) & ~(size_t)255;
        return p;
    };
    unsigned char* H1 = (unsigned char*)alloc((size_t)n * 64);  // fp8 e4m3
    unsigned char* H2 = (unsigned char*)alloc((size_t)n * 32);
    unsigned char* H3 = (unsigned char*)alloc((size_t)n * 32);
    float* B      = (float*)alloc((size_t)n * 64 * sizeof(float));  // f32 layer output
    float* ssA    = (float*)alloc((size_t)n * sizeof(float));
    float* sdA    = (float*)alloc((size_t)n * sizeof(float));
    float* ssB    = (float*)alloc((size_t)n * sizeof(float));
    float* sdB    = (float*)alloc((size_t)n * sizeof(float));
    float* ssC    = (float*)alloc((size_t)n * sizeof(float));
    float* sdC    = (float*)alloc((size_t)n * sizeof(float));
    int*   S      = (int*)alloc((size_t)total * sizeof(int));
    int*   bsums  = (int*)alloc(1024 * sizeof(int));
    int*   rowst  = (int*)alloc((size_t)(n + 1) * sizeof(int));
    int*   esrc   = (int*)alloc((size_t)E * sizeof(int));
    int*   pairs  = (int*)alloc((size_t)E * sizeof(int));
    float* facc   = (float*)alloc(64 * sizeof(float));

    // ---- CSR build (counting sort, no global atomics) + layer-1 GEMM ----
    const int ngemm1 = (n + 63) / 64;
    const int gmax = (ngemm1 > NBLK) ? ngemm1 : NBLK;
    hist_gemm1_kernel<<<2 * gmax, BLOCK, 0, stream>>>(
        x, W1, as1, ad1, H1, ssA, sdA, n, ngemm1, dstp, E, chunk, NB, S, facc);
    int nb1 = (total + 1023) / 1024;
    scan1_kernel<<<nb1, 1024, 0, stream>>>(S, total, bsums);
    scan2_kernel<<<1, 1024, 0, stream>>>(bsums, nb1);
    scatter_kernel<<<NBLK, BLOCK, 0, stream>>>(srcp, dstp, E, chunk, NB, S, bsums, pairs);
    bucket_csr_kernel<<<NB, BLOCK, 0, stream>>>(pairs, S, bsums, NB, n, E, rowst, esrc);

    // ---- layer 1 aggregation (quad-column: 16 lanes/node, 16 nodes/block) ----
    gat_aggr_kernel<64, 4, 4, true><<<(n + 15) / 16, BLOCK, 0, stream>>>(
        H1, ssA, sdA, rowst, esrc, b1, B, n);

    // ---- layer 2 ----
    gemm_att_kernel<64, 32, true><<<(n + 127) / 128, BLOCK, 0, stream>>>(
        B, W2, as2, ad2, H2, ssB, sdB, n);
    gat_aggr_kernel<32, 4, 2, true><<<(n + 15) / 16, BLOCK, 0, stream>>>(
        H2, ssB, sdB, rowst, esrc, b2, B, n);

    // ---- layer 3 ----
    gemm_att_kernel<32, 32, true><<<(n + 127) / 128, BLOCK, 0, stream>>>(
        B, W3, as3, ad3, H3, ssC, sdC, n);
    gat_aggr_kernel<32, 4, 2, false><<<(n + 15) / 16, BLOCK, 0, stream>>>(
        H3, ssC, sdC, rowst, esrc, nullptr, B, n);
    mean_kernel<<<1024, 256, 0, stream>>>(B, facc, n);
    finalize_kernel<<<1, 64, 0, stream>>>(facc, b3, tdp, cansup, (float*)d_out, n);
}

// Round 20
// 197.840 us; speedup vs baseline: 1.0957x; 1.0036x over previous
//
#include <hip/hip_runtime.h>

// 3-layer GAT (PyG GATConv) on MI355X.
// CSR build via two-level counting sort — NO global atomics (R10).
//   A: per-block LDS histogram + layer-1 GEMM on even blocks.
//   scan1/scan2 (scan3 fused into consumers).
//   C: scatter packed (src|(dst&63)<<17) records, 4-deep pipelined (R20).
//   D: per-bucket CSR; bucket's pairs cached in LDS once (R20: was read
//      from global twice; avg bucket 4KB fits easily, fallback if >1536).
// Layers: gemm_att (micro-tiled LDS GEMM; epilogue emits H in FP8 e4m3 —
// R19 confirmed aggr was random-access HBM-fetch bound; fp8 halved bytes,
// attention logits stay f32) -> gat_aggr (fused softmax + gather; lane
// owns CPL adjacent fp8 columns; K=4 stash, tail-only init, stride ≡8
// mod 32 banks). Mean separate (R10+R15).

constexpr int BLOCK = 256;
constexpr int NBLK = 512;    // hist/scatter blocks (chunked edge ownership)
constexpr int BSH = 6;       // 64 nodes per bucket
constexpr int MAXNB = 1600;  // max buckets (n <= 102400)
constexpr int BCAP = 1536;   // LDS pairs cache per bucket (avg 1024, max ~1150)

__device__ __forceinline__ float llrelu(float x) { return x >= 0.f ? x : 0.2f * x; }

// ---------- GEMM body (H fp8 + attention dots), LDS provided by caller ----------
template <int FIN, int FOUT, bool RELU_IN>
__device__ __forceinline__ void gemm_att_body(
    const float* __restrict__ X, const float* __restrict__ W,
    const float* __restrict__ asrc, const float* __restrict__ adst,
    unsigned char* __restrict__ H, float* __restrict__ Ssrc,
    float* __restrict__ Sdst, int n, int gblk, float* Xs, float* Ws) {
    constexpr int CG = FOUT / 4;
    constexpr int NG = BLOCK / CG;
    constexpr int TN = NG * 4;
    constexpr int S = FIN + 4;

    int tid = threadIdx.x;
    int n0_blk = gblk * TN;

    for (int t = tid; t < FIN * FOUT / 4; t += BLOCK) {
        float4 v = ((const float4*)W)[t];
        *(float4*)&Ws[t * 4] = v;
    }
    constexpr int RW = FIN / 4;
    for (int t = tid; t < TN * RW; t += BLOCK) {
        int r = t / RW, c = t % RW;
        int gr = n0_blk + r;
        if (gr >= n) gr = n - 1;
        float4 v = ((const float4*)(X + (size_t)gr * FIN))[c];
        if (RELU_IN) {
            v.x = fmaxf(v.x, 0.f); v.y = fmaxf(v.y, 0.f);
            v.z = fmaxf(v.z, 0.f); v.w = fmaxf(v.w, 0.f);
        }
        *(float4*)&Xs[r * S + c * 4] = v;
    }
    __syncthreads();

    int tx = tid % CG, ty = tid / CG;
    int c0 = tx * 4, nloc = ty * 4;

    float acc[4][4];
#pragma unroll
    for (int i = 0; i < 4; ++i)
#pragma unroll
        for (int j = 0; j < 4; ++j) acc[i][j] = 0.f;

#pragma unroll 2
    for (int kc = 0; kc < FIN / 4; ++kc) {
        float4 xv[4], wv[4];
#pragma unroll
        for (int i = 0; i < 4; ++i) xv[i] = *(const float4*)&Xs[(nloc + i) * S + kc * 4];
#pragma unroll
        for (int kk = 0; kk < 4; ++kk) wv[kk] = *(const float4*)&Ws[(kc * 4 + kk) * FOUT + c0];
#pragma unroll
        for (int i = 0; i < 4; ++i) {
            float xi0 = xv[i].x, xi1 = xv[i].y, xi2 = xv[i].z, xi3 = xv[i].w;
            acc[i][0] = fmaf(xi0, wv[0].x, acc[i][0]);
            acc[i][1] = fmaf(xi0, wv[0].y, acc[i][1]);
            acc[i][2] = fmaf(xi0, wv[0].z, acc[i][2]);
            acc[i][3] = fmaf(xi0, wv[0].w, acc[i][3]);
            acc[i][0] = fmaf(xi1, wv[1].x, acc[i][0]);
            acc[i][1] = fmaf(xi1, wv[1].y, acc[i][1]);
            acc[i][2] = fmaf(xi1, wv[1].z, acc[i][2]);
            acc[i][3] = fmaf(xi1, wv[1].w, acc[i][3]);
            acc[i][0] = fmaf(xi2, wv[2].x, acc[i][0]);
            acc[i][1] = fmaf(xi2, wv[2].y, acc[i][1]);
            acc[i][2] = fmaf(xi2, wv[2].z, acc[i][2]);
            acc[i][3] = fmaf(xi2, wv[2].w, acc[i][3]);
            acc[i][0] = fmaf(xi3, wv[3].x, acc[i][0]);
            acc[i][1] = fmaf(xi3, wv[3].y, acc[i][1]);
            acc[i][2] = fmaf(xi3, wv[3].z, acc[i][2]);
            acc[i][3] = fmaf(xi3, wv[3].w, acc[i][3]);
        }
    }

    float4 as4 = *(const float4*)&asrc[c0];
    float4 ad4 = *(const float4*)&adst[c0];

#pragma unroll
    for (int i = 0; i < 4; ++i) {
        int node = n0_blk + nloc + i;
        bool ok = node < n;
        if (ok) {
            unsigned int p = 0;
            p = __builtin_amdgcn_cvt_pk_fp8_f32(acc[i][0], acc[i][1], p, false);
            p = __builtin_amdgcn_cvt_pk_fp8_f32(acc[i][2], acc[i][3], p, true);
            *(unsigned int*)&H[(size_t)node * FOUT + c0] = p;
        }
        float vs = acc[i][0] * as4.x + acc[i][1] * as4.y + acc[i][2] * as4.z + acc[i][3] * as4.w;
        float vd = acc[i][0] * ad4.x + acc[i][1] * ad4.y + acc[i][2] * ad4.z + acc[i][3] * ad4.w;
#pragma unroll
        for (int off = CG / 2; off > 0; off >>= 1) {
            vs += __shfl_xor(vs, off, CG);
            vd += __shfl_xor(vd, off, CG);
        }
        if (tx == 0 && ok) {
            Ssrc[node] = vs;
            Sdst[node] = vd;
        }
    }
}

template <int FIN, int FOUT, bool RELU_IN>
__global__ void gemm_att_kernel(const float* __restrict__ X, const float* __restrict__ W,
                                const float* __restrict__ asrc, const float* __restrict__ adst,
                                unsigned char* __restrict__ H, float* __restrict__ Ssrc,
                                float* __restrict__ Sdst, int n) {
    constexpr int CG = FOUT / 4;
    constexpr int NG = BLOCK / CG;
    constexpr int TN = NG * 4;
    constexpr int S = FIN + 4;
    __shared__ float Xs[TN * S];
    __shared__ float Ws[FIN * FOUT];
    gemm_att_body<FIN, FOUT, RELU_IN>(X, W, asrc, adst, H, Ssrc, Sdst, n, blockIdx.x, Xs, Ws);
}

// ---------- Phase A: coarse histogram (odd blocks) + layer-1 GEMM (even) ----------
__global__ void hist_gemm1_kernel(const float* __restrict__ X, const float* __restrict__ W,
                                  const float* __restrict__ asrc, const float* __restrict__ adst,
                                  unsigned char* __restrict__ H, float* __restrict__ Ssrc,
                                  float* __restrict__ Sdst, int n, int ngemm,
                                  const int* __restrict__ dst, int E, int chunk, int NB,
                                  int* __restrict__ S, float* __restrict__ facc) {
    // LDS union: gemm<64,64> needs 64*68 + 64*64 = 8448 floats; hist needs 1600 ints.
    __shared__ __align__(16) float lds[8448];
    int bid = blockIdx.x;
    if ((bid & 1) == 0) {
        int gb = bid >> 1;
        if (gb >= ngemm) return;
        gemm_att_body<64, 64, false>(X, W, asrc, adst, H, Ssrc, Sdst, n, gb, lds, lds + 64 * 68);
    } else {
        int k = bid >> 1;
        if (k >= NBLK) return;
        int* hist = (int*)lds;
        for (int i = threadIdx.x; i < NB; i += BLOCK) hist[i] = 0;
        if (k == 0 && threadIdx.x < 32) facc[threadIdx.x] = 0.f;
        __syncthreads();
        int start = k * chunk, end = min(E, start + chunk);
        for (int i = start + threadIdx.x; i < end; i += BLOCK)
            atomicAdd(&hist[dst[i] >> BSH], 1);
        __syncthreads();
        for (int b = threadIdx.x; b < NB; b += BLOCK) S[(size_t)b * NBLK + k] = hist[b];
    }
}

// ---------- 2-pass scan over S[NB*NBLK] (pass 3 fused into consumers) ----------
__global__ void scan1_kernel(int* __restrict__ S, int total, int* __restrict__ bsums) {
    __shared__ int s[1024];
    int tid = threadIdx.x;
    int gid = blockIdx.x * 1024 + tid;
    int v = (gid < total) ? S[gid] : 0;
    s[tid] = v;
    for (int off = 1; off < 1024; off <<= 1) {
        __syncthreads();
        int t = (tid >= off) ? s[tid - off] : 0;
        __syncthreads();
        s[tid] += t;
    }
    __syncthreads();
    if (gid < total) S[gid] = s[tid] - v;  // exclusive within block
    if (tid == 1023) bsums[blockIdx.x] = s[tid];
}

// Single-block tiled scan (handles nb > 1024 via carried offset).
__global__ void scan2_kernel(int* __restrict__ bsums, int nb) {
    __shared__ int s[1024];
    __shared__ int carry_s;
    int tid = threadIdx.x;
    if (tid == 0) carry_s = 0;
    __syncthreads();
    for (int base = 0; base < nb; base += 1024) {
        int i = base + tid;
        int v = (i < nb) ? bsums[i] : 0;
        s[tid] = v;
        for (int off = 1; off < 1024; off <<= 1) {
            __syncthreads();
            int t = (tid >= off) ? s[tid - off] : 0;
            __syncthreads();
            s[tid] += t;
        }
        __syncthreads();
        int c = carry_s;
        if (i < nb) bsums[i] = s[tid] - v + c;  // exclusive + carry
        __syncthreads();
        if (tid == 1023) carry_s = c + s[1023];
        __syncthreads();
    }
}

// ---------- Phase C: scatter packed records, 4-deep pipelined ----------
// Record: src | (dst&63)<<17  (requires n <= 131072; here n = 100000).
// Global base = S[cell] + bsums[cell>>10] (scan3 fused).
__global__ void scatter_kernel(const int* __restrict__ src, const int* __restrict__ dst,
                               int E, int chunk, int NB, const int* __restrict__ S,
                               const int* __restrict__ bsums, int* __restrict__ pairs) {
    __shared__ int cursor[MAXNB];
    int k = blockIdx.x;
    for (int b = threadIdx.x; b < NB; b += BLOCK) {
        int cell = b * NBLK + k;
        cursor[b] = S[cell] + bsums[cell >> 10];
    }
    __syncthreads();
    int start = k * chunk, end = min(E, start + chunk);
    for (int i = start + threadIdx.x; i < end; i += 4 * BLOCK) {
        int idx[4], d[4], sv[4], pos[4];
        bool ok[4];
#pragma unroll
        for (int u = 0; u < 4; ++u) {
            idx[u] = i + u * BLOCK;
            ok[u] = idx[u] < end;
            int safe = ok[u] ? idx[u] : start;
            d[u] = dst[safe];
            sv[u] = src[safe];
        }
#pragma unroll
        for (int u = 0; u < 4; ++u)
            if (ok[u]) pos[u] = atomicAdd(&cursor[d[u] >> BSH], 1);
#pragma unroll
        for (int u = 0; u < 4; ++u)
            if (ok[u]) pairs[pos[u]] = sv[u] | ((d[u] & 63) << 17);
    }
}

// ---------- Phase D: per-bucket CSR; bucket pairs cached in LDS ----------
__global__ void bucket_csr_kernel(const int* __restrict__ pairs, const int* __restrict__ S,
                                  const int* __restrict__ bsums, int NB, int n, int E,
                                  int* __restrict__ rowst, int* __restrict__ esrc) {
    __shared__ int cnt[64], excl[64];
    __shared__ int plds[BCAP];
    int b = blockIdx.x;
    if (b >= NB) return;
    int g0 = b * NBLK;
    int base = S[g0] + bsums[g0 >> 10];
    int end = E;
    if (b + 1 < NB) {
        int g1 = (b + 1) * NBLK;
        end = S[g1] + bsums[g1 >> 10];
    }
    int m = end - base;
    bool fits = (m <= BCAP);
    if (fits)
        for (int i = threadIdx.x; i < m; i += BLOCK) plds[i] = pairs[base + i];
    if (threadIdx.x < 64) cnt[threadIdx.x] = 0;
    __syncthreads();
    for (int i = threadIdx.x; i < m; i += BLOCK) {
        int p = fits ? plds[i] : pairs[base + i];
        atomicAdd(&cnt[p >> 17], 1);
    }
    __syncthreads();
    if (threadIdx.x == 0) {
        int run = 0;
        for (int j = 0; j < 64; ++j) { excl[j] = run; run += cnt[j]; }
    }
    __syncthreads();
    int node0 = b << BSH;
    if (threadIdx.x < 64) {
        int node = node0 + threadIdx.x;
        if (node < n) rowst[node] = base + excl[threadIdx.x];
        cnt[threadIdx.x] = excl[threadIdx.x];  // becomes the running cursor
    }
    if (b == NB - 1 && threadIdx.x == 0) rowst[n] = E;
    __syncthreads();
    for (int i = threadIdx.x; i < m; i += BLOCK) {
        int p = fits ? plds[i] : pairs[base + i];
        int pos = atomicAdd(&cnt[p >> 17], 1);  // LDS returning atomic
        esrc[base + pos] = p & 0x1FFFF;
    }
}

// ---------- CPL-column gather machinery (fp8 e4m3 unpack via HW cvt) ----------
template <int CPL> struct GatherT;
template <> struct GatherT<2> { using T = unsigned short; };  // 2 fp8
template <> struct GatherT<4> { using T = unsigned int; };    // 4 fp8

__device__ __forceinline__ void unpack_fma(unsigned short p, float w, float* acc) {
    unsigned int u = p;
    acc[0] = fmaf(w, __builtin_amdgcn_cvt_f32_fp8(u, 0), acc[0]);
    acc[1] = fmaf(w, __builtin_amdgcn_cvt_f32_fp8(u, 1), acc[1]);
}
__device__ __forceinline__ void unpack_fma(unsigned int p, float w, float* acc) {
    acc[0] = fmaf(w, __builtin_amdgcn_cvt_f32_fp8(p, 0), acc[0]);
    acc[1] = fmaf(w, __builtin_amdgcn_cvt_f32_fp8(p, 1), acc[1]);
    acc[2] = fmaf(w, __builtin_amdgcn_cvt_f32_fp8(p, 2), acc[2]);
    acc[3] = fmaf(w, __builtin_amdgcn_cvt_f32_fp8(p, 3), acc[3]);
}

template <int NBATCH, typename GT>
__device__ __forceinline__ void gather_fma_b(const GT* __restrict__ Hg,
                                             const float* wldsg, const int* ildsg,
                                             int j0, int lane, float* acc) {
    float wv[NBATCH];
    int ix[NBATCH];
#pragma unroll
    for (int q = 0; q < NBATCH / 4; ++q) {
        float4 w = *(const float4*)&wldsg[j0 + q * 4];
        int4 i4 = *(const int4*)&ildsg[j0 + q * 4];
        wv[q * 4 + 0] = w.x; wv[q * 4 + 1] = w.y; wv[q * 4 + 2] = w.z; wv[q * 4 + 3] = w.w;
        ix[q * 4 + 0] = i4.x; ix[q * 4 + 1] = i4.y; ix[q * 4 + 2] = i4.z; ix[q * 4 + 3] = i4.w;
    }
    GT pv[NBATCH];
#pragma unroll
    for (int u = 0; u < NBATCH; ++u) pv[u] = Hg[(size_t)(unsigned)(ix[u] + lane)];
#pragma unroll
    for (int u = 0; u < NBATCH; ++u) unpack_fma(pv[u], wv[u], acc);
}

// ---------- fused softmax + gather core (CPL columns per lane) ----------
// LPN = F/CPL lanes serve one node; lane owns columns [CPL*lane, CPL*lane+CPL).
// Init covers only [deg, R) — the exact tail pass-3 reads.
template <int F, int K, int CPL>
__device__ __forceinline__ void aggr_node_core(
    const unsigned char* __restrict__ H, const float* __restrict__ Ssrc,
    const float* __restrict__ Sdst, const int* __restrict__ row_start,
    const int* __restrict__ esrc, int node, int lane,
    float* wldsg, int* ildsg, float* accOut) {
    constexpr int LPN = F / CPL;
    constexpr int NS = K * LPN;
    using GT = typename GatherT<CPL>::T;
    const GT* Hg = (const GT*)H;
    int rs = row_start[node];
    int deg = row_start[node + 1] - rs;
    float sdi = Sdst[node];
    float selft = llrelu(Ssrc[node] + sdi);

    // pass-3 read extent R (16-batches + one 16/8 tail), then tail init
    int nbv = deg < NS ? deg : NS;
    int nb16 = nbv & ~15;
    int rem = nbv - nb16;
    int R = nb16 + (rem > 8 ? 16 : (rem > 0 ? 8 : 0));
    for (int j = deg + lane; j < R; j += LPN) {
        wldsg[j] = 0.f;
        ildsg[j] = node * LPN;  // own row (safe zero-weight tail)
    }

    float wreg[K];
    float m = selft;
#pragma unroll
    for (int k = 0; k < K; ++k) {
        int j = k * LPN + lane;
        if (j < deg) {
            int s = esrc[rs + j];
            float t = llrelu(Ssrc[s] + sdi);
            ildsg[j] = s * LPN;
            wreg[k] = t;
            m = fmaxf(m, t);
        }
    }
    for (int j = NS + lane; j < deg; j += LPN)  // overflow (deg > NS): rare
        m = fmaxf(m, llrelu(Ssrc[esrc[rs + j]] + sdi));
#pragma unroll
    for (int off = LPN / 2; off > 0; off >>= 1) m = fmaxf(m, __shfl_xor(m, off, LPN));

    float selfw = __expf(selft - m);
    float l = (lane == 0) ? selfw : 0.f;
#pragma unroll
    for (int k = 0; k < K; ++k) {
        int j = k * LPN + lane;
        if (j < deg) {
            float e = __expf(wreg[k] - m);
            wldsg[j] = e;
            l += e;
        }
    }
    for (int j = NS + lane; j < deg; j += LPN)
        l += __expf(llrelu(Ssrc[esrc[rs + j]] + sdi) - m);
#pragma unroll
    for (int off = LPN / 2; off > 0; off >>= 1) l += __shfl_xor(l, off, LPN);
    float winv = 1.f / l;

    float acc[CPL];
#pragma unroll
    for (int c = 0; c < CPL; ++c) acc[c] = 0.f;
    GT pself = Hg[(size_t)node * LPN + lane];
    unpack_fma(pself, selfw, acc);

    // pass 3: full 16-slot batches + 8-slot tail (uniform per group).
    int j0 = 0;
    for (; j0 < nb16; j0 += 16) gather_fma_b<16, GT>(Hg, wldsg, ildsg, j0, lane, acc);
    if (rem > 8) gather_fma_b<16, GT>(Hg, wldsg, ildsg, j0, lane, acc);
    else if (rem > 0) gather_fma_b<8, GT>(Hg, wldsg, ildsg, j0, lane, acc);

    for (int j = NS; j < deg; ++j) {  // overflow: recompute w_j (rare)
        int s = esrc[rs + j];
        float wj = __expf(llrelu(Ssrc[s] + sdi) - m);
        GT p = Hg[(size_t)s * LPN + lane];
        unpack_fma(p, wj, acc);
    }
#pragma unroll
    for (int c = 0; c < CPL; ++c) accOut[c] = acc[c] * winv;
}

// Standalone aggregation: LPN=F/CPL lanes per node, CPL floats out per lane.
// Stash stride NSP = NS + 8 floats (≡8 mod 32 banks).
template <int F, int K, int CPL, bool WITH_BIAS>
__global__ void gat_aggr_kernel(const unsigned char* __restrict__ H,
                                const float* __restrict__ Ssrc, const float* __restrict__ Sdst,
                                const int* __restrict__ rowst, const int* __restrict__ esrc,
                                const float* __restrict__ bias, float* __restrict__ OUT, int n) {
    constexpr int LPN = F / CPL;
    constexpr int GPB = BLOCK / LPN;
    constexpr int NSP = K * LPN + 8;  // padded stride (8 floats = 32 B)
    __shared__ __align__(16) float wlds[GPB][NSP];
    __shared__ __align__(16) int ilds[GPB][NSP];
    int tid = threadIdx.x;
    int grp = tid / LPN, lane = tid % LPN;
    int node = blockIdx.x * GPB + grp;
    if (node >= n) return;
    float acc[CPL];
    aggr_node_core<F, K, CPL>(H, Ssrc, Sdst, rowst, esrc, node, lane,
                              wlds[grp], ilds[grp], acc);
    if (WITH_BIAS) {
#pragma unroll
        for (int c = 0; c < CPL; ++c) acc[c] += bias[CPL * lane + c];
    }
    if constexpr (CPL == 4) {
        float4 v = make_float4(acc[0], acc[1], acc[2], acc[3]);
        *(float4*)&OUT[(size_t)node * F + 4 * lane] = v;
    } else {
        float2 v = make_float2(acc[0], acc[1]);
        *(float2*)&OUT[(size_t)node * F + 2 * lane] = v;
    }
}

// Sum OUT3 over nodes into facc[32].
__global__ void mean_kernel(const float* __restrict__ B, float* __restrict__ facc, int n) {
    __shared__ float s[32];
    int lane = threadIdx.x & 31, row = threadIdx.x >> 5;
    float a = 0.f;
    for (int node = blockIdx.x * 8 + row; node < n; node += gridDim.x * 8)
        a += B[(size_t)node * 32 + lane];
    if (threadIdx.x < 32) s[threadIdx.x] = 0.f;
    __syncthreads();
    atomicAdd(&s[lane], a);
    __syncthreads();
    if (threadIdx.x < 32) atomicAdd(&facc[threadIdx.x], s[threadIdx.x]);
}

__global__ void finalize_kernel(const float* __restrict__ facc, const float* __restrict__ b,
                                const float* __restrict__ tdp, const float* __restrict__ cansup,
                                float* __restrict__ out, int n) {
    int f = threadIdx.x;
    if (f < 32) {
        float td = tdp[0] * cansup[0];
        out[f] = (facc[f] / (float)n + b[f]) * td;
    }
}

extern "C" void kernel_launch(void* const* d_in, const int* in_sizes, int n_in,
                              void* d_out, int out_size, void* d_ws, size_t ws_size,
                              hipStream_t stream) {
    const float* x      = (const float*)d_in[0];
    const int* eidx     = (const int*)d_in[1];
    const float* W1     = (const float*)d_in[2];
    const float* as1    = (const float*)d_in[3];
    const float* ad1    = (const float*)d_in[4];
    const float* b1     = (const float*)d_in[5];
    const float* W2     = (const float*)d_in[6];
    const float* as2    = (const float*)d_in[7];
    const float* ad2    = (const float*)d_in[8];
    const float* b2     = (const float*)d_in[9];
    const float* W3     = (const float*)d_in[10];
    const float* as3    = (const float*)d_in[11];
    const float* ad3    = (const float*)d_in[12];
    const float* b3     = (const float*)d_in[13];
    const float* tdp    = (const float*)d_in[14];
    const float* cansup = (const float*)d_in[15];

    const int n = in_sizes[0] / 64;   // 100000 nodes
    const int E = in_sizes[1] / 2;    // 1600000 edges
    const int* srcp = eidx;
    const int* dstp = eidx + E;

    const int NB = (n + 63) >> BSH;           // 1563 buckets
    const int chunk = (E + NBLK - 1) / NBLK;  // edges per hist/scatter block
    const int total = NB * NBLK;              // scan matrix size

    char* ws = (char*)d_ws;
    size_t off = 0;
    auto alloc = [&](size_t bytes) -> void* {
        void* p = ws + off;
        off += (bytes + 255) & ~(size_t)255;
        return p;
    };
    unsigned char* H1 = (unsigned char*)alloc((size_t)n * 64);  // fp8 e4m3
    unsigned char* H2 = (unsigned char*)alloc((size_t)n * 32);
    unsigned char* H3 = (unsigned char*)alloc((size_t)n * 32);
    float* B      = (float*)alloc((size_t)n * 64 * sizeof(float));  // f32 layer output
    float* ssA    = (float*)alloc((size_t)n * sizeof(float));
    float* sdA    = (float*)alloc((size_t)n * sizeof(float));
    float* ssB    = (float*)alloc((size_t)n * sizeof(float));
    float* sdB    = (float*)alloc((size_t)n * sizeof(float));
    float* ssC    = (float*)alloc((size_t)n * sizeof(float));
    float* sdC    = (float*)alloc((size_t)n * sizeof(float));
    int*   S      = (int*)alloc((size_t)total * sizeof(int));
    int*   bsums  = (int*)alloc(1024 * sizeof(int));
    int*   rowst  = (int*)alloc((size_t)(n + 1) * sizeof(int));
    int*   esrc   = (int*)alloc((size_t)E * sizeof(int));
    int*   pairs  = (int*)alloc((size_t)E * sizeof(int));
    float* facc   = (float*)alloc(64 * sizeof(float));

    // ---- CSR build (counting sort, no global atomics) + layer-1 GEMM ----
    const int ngemm1 = (n + 63) / 64;
    const int gmax = (ngemm1 > NBLK) ? ngemm1 : NBLK;
    hist_gemm1_kernel<<<2 * gmax, BLOCK, 0, stream>>>(
        x, W1, as1, ad1, H1, ssA, sdA, n, ngemm1, dstp, E, chunk, NB, S, facc);
    int nb1 = (total + 1023) / 1024;
    scan1_kernel<<<nb1, 1024, 0, stream>>>(S, total, bsums);
    scan2_kernel<<<1, 1024, 0, stream>>>(bsums, nb1);
    scatter_kernel<<<NBLK, BLOCK, 0, stream>>>(srcp, dstp, E, chunk, NB, S, bsums, pairs);
    bucket_csr_kernel<<<NB, BLOCK, 0, stream>>>(pairs, S, bsums, NB, n, E, rowst, esrc);

    // ---- layer 1 aggregation (quad-column: 16 lanes/node, 16 nodes/block) ----
    gat_aggr_kernel<64, 4, 4, true><<<(n + 15) / 16, BLOCK, 0, stream>>>(
        H1, ssA, sdA, rowst, esrc, b1, B, n);

    // ---- layer 2 ----
    gemm_att_kernel<64, 32, true><<<(n + 127) / 128, BLOCK, 0, stream>>>(
        B, W2, as2, ad2, H2, ssB, sdB, n);
    gat_aggr_kernel<32, 4, 2, true><<<(n + 15) / 16, BLOCK, 0, stream>>>(
        H2, ssB, sdB, rowst, esrc, b2, B, n);

    // ---- layer 3 ----
    gemm_att_kernel<32, 32, true><<<(n + 127) / 128, BLOCK, 0, stream>>>(
        B, W3, as3, ad3, H3, ssC, sdC, n);
    gat_aggr_kernel<32, 4, 2, false><<<(n + 15) / 16, BLOCK, 0, stream>>>(
        H3, ssC, sdC, rowst, esrc, nullptr, B, n);
    mean_kernel<<<1024, 256, 0, stream>>>(B, facc, n);
    finalize_kernel<<<1, 64, 0, stream>>>(facc, b3, tdp, cansup, (float*)d_out, n);
}